// Round 1
// baseline (2611.534 us; speedup 1.0000x reference)
//
#include <hip/hip_runtime.h>
#include <math.h>

#define N_NODES 50000
#define N_EDGES 800000
#define EP (N_EDGES + N_NODES)   // edges + self loops
#define IN_DIM 128
#define HID 64
#define HEADS 2
#define OUT_DIM 2
#define N_GRAPHS 512
#define NEG_SLOPE 0.2f

// ---- order-preserving float<->uint for atomic max ----
__device__ __forceinline__ unsigned enc_f(float f) {
    unsigned u = __float_as_uint(f);
    return (u & 0x80000000u) ? ~u : (u | 0x80000000u);
}
__device__ __forceinline__ float dec_f(unsigned u) {
    return (u & 0x80000000u) ? __uint_as_float(u & 0x7FFFFFFFu)
                             : __uint_as_float(~u);
}
#define ENC_NEG_INF 0x007FFFFFu   // enc_f(-inf)

__global__ void init_emax_kernel(unsigned* __restrict__ p, int n) {
    int i = blockIdx.x * blockDim.x + threadIdx.x;
    if (i < n) p[i] = ENC_NEG_INF;
}

// Y[n][j] = sum_k X[n][k] * W[k][j];  COLS threads, NPB nodes per block
template<int K, int COLS, int NPB>
__global__ void gemm_nodes(const float* __restrict__ X, const float* __restrict__ W,
                           float* __restrict__ Y, int n_nodes) {
    __shared__ float xs[NPB][K];
    const int base = blockIdx.x * NPB;
    const int tid = threadIdx.x;
    for (int idx = tid; idx < NPB * K; idx += COLS) {
        int r = idx / K, c = idx % K;
        int n = base + r;
        xs[r][c] = (n < n_nodes) ? X[(size_t)n * K + c] : 0.f;
    }
    __syncthreads();
    float acc[NPB];
#pragma unroll
    for (int i = 0; i < NPB; i++) acc[i] = 0.f;
    for (int k = 0; k < K; k++) {
        float w = W[(size_t)k * COLS + tid];
#pragma unroll
        for (int i = 0; i < NPB; i++) acc[i] = fmaf(xs[i][k], w, acc[i]);
    }
#pragma unroll
    for (int i = 0; i < NPB; i++) {
        int n = base + i;
        if (n < n_nodes) Y[(size_t)n * COLS + tid] = acc[i];
    }
}

// per-node attention logits: as[i][h] = <h[i,h,:], a_src[h,:]>, ad likewise
template<int H>
__global__ void alphas_kernel(const float* __restrict__ Hf,
                              const float* __restrict__ a_src,
                              const float* __restrict__ a_dst,
                              float* __restrict__ as, float* __restrict__ ad, int n) {
    int i = blockIdx.x * blockDim.x + threadIdx.x;
    if (i >= n) return;
#pragma unroll
    for (int h = 0; h < H; h++) {
        const float* hp = Hf + (size_t)i * (H * HID) + h * HID;
        float s = 0.f, d = 0.f;
#pragma unroll 8
        for (int c = 0; c < HID; c++) {
            float v = hp[c];
            s = fmaf(v, a_src[h * HID + c], s);
            d = fmaf(v, a_dst[h * HID + c], d);
        }
        as[(size_t)i * H + h] = s;
        ad[(size_t)i * H + h] = d;
    }
}

template<int H>
__global__ void edge_max_kernel(const int* __restrict__ ei,
                                const float* __restrict__ as, const float* __restrict__ ad,
                                float* __restrict__ ebuf, unsigned* __restrict__ emax) {
    int i = blockIdx.x * blockDim.x + threadIdx.x;
    if (i >= EP) return;
    int s, d;
    if (i < N_EDGES) { s = ei[i]; d = ei[N_EDGES + i]; }
    else             { s = d = i - N_EDGES; }
#pragma unroll
    for (int h = 0; h < H; h++) {
        float e = as[(size_t)s * H + h] + ad[(size_t)d * H + h];
        e = (e > 0.f) ? e : NEG_SLOPE * e;   // leaky relu
        ebuf[(size_t)i * H + h] = e;
        atomicMax(&emax[(size_t)d * H + h], enc_f(e));
    }
}

template<int H>
__global__ void edge_exp_kernel(const int* __restrict__ ei,
                                float* __restrict__ ebuf,
                                const unsigned* __restrict__ emax,
                                float* __restrict__ denom) {
    int i = blockIdx.x * blockDim.x + threadIdx.x;
    if (i >= EP) return;
    int d = (i < N_EDGES) ? ei[N_EDGES + i] : (i - N_EDGES);
#pragma unroll
    for (int h = 0; h < H; h++) {
        float ex = expf(ebuf[(size_t)i * H + h] - dec_f(emax[(size_t)d * H + h]));
        ebuf[(size_t)i * H + h] = ex;
        atomicAdd(&denom[(size_t)d * H + h], ex);
    }
}

// out[dst][h][c] += h[src][h][c] * (ex / denom[dst][h]); 4 channels per lane
template<int H>
__global__ void edge_agg_kernel(const int* __restrict__ ei,
                                const float* __restrict__ Hf,
                                const float* __restrict__ ebuf,
                                const float* __restrict__ denom,
                                float* __restrict__ out) {
    const int VALS = H * HID;      // 128 or 64
    const int LPE = VALS / 4;      // lanes per edge
    int t = blockIdx.x * blockDim.x + threadIdx.x;
    int e = t / LPE;
    int l = t % LPE;
    if (e >= EP) return;
    int s, d;
    if (e < N_EDGES) { s = ei[e]; d = ei[N_EDGES + e]; }
    else             { s = d = e - N_EDGES; }
    int h = (l * 4) / HID;
    float coef = ebuf[(size_t)e * H + h] / denom[(size_t)d * H + h];
    const float4 hv = *(const float4*)(Hf + (size_t)s * VALS + l * 4);
    float* op = out + (size_t)d * VALS + l * 4;
    atomicAdd(op + 0, hv.x * coef);
    atomicAdd(op + 1, hv.y * coef);
    atomicAdd(op + 2, hv.z * coef);
    atomicAdd(op + 3, hv.w * coef);
}

__global__ void bias_relu_kernel(float* __restrict__ io, const float* __restrict__ b,
                                 int total, int cols) {
    int i = blockIdx.x * blockDim.x + threadIdx.x;
    if (i >= total) return;
    float v = io[i] + b[i % cols];
    io[i] = (v > 0.f) ? v : 0.f;
}

// one block per graph: binary-search node range, mean-pool, FC, log_softmax
__global__ void pool_fc_kernel(const float* __restrict__ act2,
                               const int* __restrict__ batch,
                               const float* __restrict__ fcW,
                               const float* __restrict__ fcb,
                               float* __restrict__ out) {
    int g = blockIdx.x;
    int c = threadIdx.x;   // 64 threads
    __shared__ int slo, shi;
    if (c == 0) {
        int lo = 0, hi = N_NODES;
        while (lo < hi) { int m = (lo + hi) >> 1; if (batch[m] < g) lo = m + 1; else hi = m; }
        slo = lo;
        lo = 0; hi = N_NODES;
        while (lo < hi) { int m = (lo + hi) >> 1; if (batch[m] < g + 1) lo = m + 1; else hi = m; }
        shi = lo;
    }
    __syncthreads();
    const int lo = slo, hi = shi;
    float sum = 0.f;
    for (int n = lo; n < hi; n++) sum += act2[(size_t)n * HID + c];
    float cnt = (float)(hi - lo);
    __shared__ float ps[HID];
    ps[c] = sum / fmaxf(cnt, 1.f);
    __syncthreads();
    __shared__ float ls[OUT_DIM];
    if (c < OUT_DIM) {
        float l = fcb[c];
#pragma unroll 8
        for (int k = 0; k < HID; k++) l = fmaf(ps[k], fcW[k * OUT_DIM + c], l);
        ls[c] = l;
    }
    __syncthreads();
    if (c < OUT_DIM) {
        float m = fmaxf(ls[0], ls[1]);
        float lse = m + logf(expf(ls[0] - m) + expf(ls[1] - m));
        out[(size_t)g * OUT_DIM + c] = ls[c] - lse;
    }
}

extern "C" void kernel_launch(void* const* d_in, const int* in_sizes, int n_in,
                              void* d_out, int out_size, void* d_ws, size_t ws_size,
                              hipStream_t stream) {
    const float* x    = (const float*)d_in[0];
    const int*   ei   = (const int*)d_in[1];
    const int*   batch= (const int*)d_in[2];
    const float* W1   = (const float*)d_in[3];
    const float* as1w = (const float*)d_in[4];
    const float* ad1w = (const float*)d_in[5];
    const float* b1   = (const float*)d_in[6];
    const float* W2   = (const float*)d_in[7];
    const float* as2w = (const float*)d_in[8];
    const float* ad2w = (const float*)d_in[9];
    const float* b2   = (const float*)d_in[10];
    const float* fcW  = (const float*)d_in[11];
    const float* fcb  = (const float*)d_in[12];

    const size_t N = N_NODES;
    float* ws = (float*)d_ws;
    float* h1    = ws;                       // N*128
    float* act1  = h1   + N * 128;           // N*128   (zero-init, aggregation target)
    float* out2  = act1 + N * 128;           // N*64    (zero-init)
    float* den1  = out2 + N * 64;            // N*2     (zero-init)
    float* den2  = den1 + N * 2;             // N       (zero-init)
    unsigned* emax1 = (unsigned*)(den2 + N); // N*2     (init enc(-inf))
    unsigned* emax2 = emax1 + N * 2;         // N
    float* alps1 = (float*)(emax2 + N);      // N*2
    float* alpd1 = alps1 + N * 2;            // N*2
    float* alps2 = alpd1 + N * 2;            // N
    float* alpd2 = alps2 + N;                // N
    float* ebuf  = alpd2 + N;                // EP*2 (layer2 reuses first EP)
    float* h2    = ebuf + (size_t)EP * 2;    // N*64

    // zero-init region: act1,out2,den1,den2 are contiguous = N*(128+64+2+1)
    hipMemsetAsync(act1, 0, N * 195 * sizeof(float), stream);
    init_emax_kernel<<<(N * 3 + 255) / 256, 256, 0, stream>>>(emax1, (int)(N * 3));

    // ---- layer 1 (H=2) ----
    gemm_nodes<128, 128, 4><<<(N + 3) / 4, 128, 0, stream>>>(x, W1, h1, (int)N);
    alphas_kernel<2><<<(N + 255) / 256, 256, 0, stream>>>(h1, as1w, ad1w, alps1, alpd1, (int)N);
    edge_max_kernel<2><<<(EP + 255) / 256, 256, 0, stream>>>(ei, alps1, alpd1, ebuf, emax1);
    edge_exp_kernel<2><<<(EP + 255) / 256, 256, 0, stream>>>(ei, ebuf, emax1, den1);
    edge_agg_kernel<2><<<((size_t)EP * 32 + 255) / 256, 256, 0, stream>>>(ei, h1, ebuf, den1, act1);
    bias_relu_kernel<<<(N * 128 + 255) / 256, 256, 0, stream>>>(act1, b1, (int)(N * 128), 128);

    // ---- layer 2 (H=1) ----
    gemm_nodes<128, 64, 8><<<(N + 7) / 8, 64, 0, stream>>>(act1, W2, h2, (int)N);
    alphas_kernel<1><<<(N + 255) / 256, 256, 0, stream>>>(h2, as2w, ad2w, alps2, alpd2, (int)N);
    edge_max_kernel<1><<<(EP + 255) / 256, 256, 0, stream>>>(ei, alps2, alpd2, ebuf, emax2);
    edge_exp_kernel<1><<<(EP + 255) / 256, 256, 0, stream>>>(ei, ebuf, emax2, den2);
    edge_agg_kernel<1><<<((size_t)EP * 16 + 255) / 256, 256, 0, stream>>>(ei, h2, ebuf, den2, out2);
    bias_relu_kernel<<<(N * 64 + 255) / 256, 256, 0, stream>>>(out2, b2, (int)(N * 64), 64);

    // ---- pool + fc + log_softmax ----
    pool_fc_kernel<<<N_GRAPHS, 64, 0, stream>>>(out2, batch, fcW, fcb, (float*)d_out);
}

// Round 2
// 584.149 us; speedup vs baseline: 4.4707x; 4.4707x over previous
//
#include <hip/hip_runtime.h>
#include <math.h>

#define N_NODES 50000
#define N_EDGES 800000
#define EP (N_EDGES + N_NODES)   // edges + self loops
#define IN_DIM 128
#define HID 64
#define HEADS 2
#define OUT_DIM 2
#define N_GRAPHS 512
#define NEG_SLOPE 0.2f

// ---------- CSR build ----------
__global__ void hist_kernel(const int* __restrict__ ei, int* __restrict__ cnt) {
    int i = blockIdx.x * blockDim.x + threadIdx.x;
    if (i >= EP) return;
    int d = (i < N_EDGES) ? ei[N_EDGES + i] : (i - N_EDGES);
    atomicAdd(&cnt[d], 1);
}

// single-block exclusive scan over 50K counts -> rowptr + cursor copy
__global__ void scan_kernel(const int* __restrict__ cnt, int* __restrict__ rowptr,
                            int* __restrict__ cursor) {
    __shared__ int sh[1024];
    __shared__ int sbase;
    int tid = threadIdx.x;
    if (tid == 0) sbase = 0;
    __syncthreads();
    for (int base_i = 0; base_i < N_NODES; base_i += 1024) {
        int i = base_i + tid;
        int v = (i < N_NODES) ? cnt[i] : 0;
        sh[tid] = v;
        __syncthreads();
        for (int off = 1; off < 1024; off <<= 1) {
            int t = (tid >= off) ? sh[tid - off] : 0;
            __syncthreads();
            sh[tid] += t;
            __syncthreads();
        }
        int incl = sh[tid];
        int b = sbase;
        int tot = sh[1023];
        __syncthreads();
        if (i < N_NODES) { int r = b + incl - v; rowptr[i] = r; cursor[i] = r; }
        if (tid == 0) sbase = b + tot;
        __syncthreads();
    }
    if (tid == 0) rowptr[N_NODES] = sbase;
}

__global__ void scatter_kernel(const int* __restrict__ ei, int* __restrict__ cursor,
                               int* __restrict__ csr_src) {
    int i = blockIdx.x * blockDim.x + threadIdx.x;
    if (i >= EP) return;
    int s, d;
    if (i < N_EDGES) { s = ei[i]; d = ei[N_EDGES + i]; }
    else             { s = d = i - N_EDGES; }
    int pos = atomicAdd(&cursor[d], 1);
    csr_src[pos] = s;
}

// ---------- dense ----------
// Y[n][j] = sum_k X[n][k] * W[k][j];  COLS threads, NPB nodes per block
template<int K, int COLS, int NPB>
__global__ void gemm_nodes(const float* __restrict__ X, const float* __restrict__ W,
                           float* __restrict__ Y, int n_nodes) {
    __shared__ float xs[NPB][K];
    const int base = blockIdx.x * NPB;
    const int tid = threadIdx.x;
    const float4* X4 = (const float4*)X;
    for (int idx = tid; idx < NPB * (K / 4); idx += COLS) {
        int r = idx / (K / 4), c = idx % (K / 4);
        int n = base + r;
        float4 v = (n < n_nodes) ? X4[(size_t)n * (K / 4) + c] : make_float4(0.f, 0.f, 0.f, 0.f);
        ((float4*)xs[r])[c] = v;
    }
    __syncthreads();
    float acc[NPB];
#pragma unroll
    for (int i = 0; i < NPB; i++) acc[i] = 0.f;
    for (int k = 0; k < K; k++) {
        float w = W[(size_t)k * COLS + tid];
#pragma unroll
        for (int i = 0; i < NPB; i++) acc[i] = fmaf(xs[i][k], w, acc[i]);
    }
#pragma unroll
    for (int i = 0; i < NPB; i++) {
        int n = base + i;
        if (n < n_nodes) Y[(size_t)n * COLS + tid] = acc[i];
    }
}

template<int H>
__global__ void alphas_kernel(const float* __restrict__ Hf,
                              const float* __restrict__ a_src,
                              const float* __restrict__ a_dst,
                              float* __restrict__ as, float* __restrict__ ad, int n) {
    int i = blockIdx.x * blockDim.x + threadIdx.x;
    if (i >= n) return;
#pragma unroll
    for (int h = 0; h < H; h++) {
        const float* hp = Hf + (size_t)i * (H * HID) + h * HID;
        float s = 0.f, d = 0.f;
#pragma unroll 8
        for (int c = 0; c < HID; c++) {
            float v = hp[c];
            s = fmaf(v, a_src[h * HID + c], s);
            d = fmaf(v, a_dst[h * HID + c], d);
        }
        as[(size_t)i * H + h] = s;
        ad[(size_t)i * H + h] = d;
    }
}

__device__ __forceinline__ float lrelu(float e) { return e > 0.f ? e : NEG_SLOPE * e; }

// ---------- fused per-node softmax + aggregate + bias + relu ----------
// layer 1: H=2, one wave per node, lane owns channels (lane) and (lane+64)
__global__ void node_agg1_kernel(const int* __restrict__ rowptr, const int* __restrict__ csr_src,
                                 const float* __restrict__ Hf,
                                 const float* __restrict__ as, const float* __restrict__ ad,
                                 const float* __restrict__ b, float* __restrict__ outp) {
    int wave = threadIdx.x >> 6;
    int lane = threadIdx.x & 63;
    int node = blockIdx.x * 4 + wave;
    if (node >= N_NODES) return;
    const int lo = rowptr[node], hi = rowptr[node + 1];
    const float ad0 = ad[(size_t)node * 2 + 0], ad1 = ad[(size_t)node * 2 + 1];

    float m0 = -INFINITY, m1 = -INFINITY;
    for (int j = lo + lane; j < hi; j += 64) {
        int s = csr_src[j];
        m0 = fmaxf(m0, lrelu(as[(size_t)s * 2 + 0] + ad0));
        m1 = fmaxf(m1, lrelu(as[(size_t)s * 2 + 1] + ad1));
    }
#pragma unroll
    for (int off = 32; off; off >>= 1) {
        m0 = fmaxf(m0, __shfl_xor(m0, off));
        m1 = fmaxf(m1, __shfl_xor(m1, off));
    }
    float d0 = 0.f, d1 = 0.f;
    for (int j = lo + lane; j < hi; j += 64) {
        int s = csr_src[j];
        d0 += expf(lrelu(as[(size_t)s * 2 + 0] + ad0) - m0);
        d1 += expf(lrelu(as[(size_t)s * 2 + 1] + ad1) - m1);
    }
#pragma unroll
    for (int off = 32; off; off >>= 1) {
        d0 += __shfl_xor(d0, off);
        d1 += __shfl_xor(d1, off);
    }
    const float inv0 = 1.f / d0, inv1 = 1.f / d1;

    float acc0 = 0.f, acc1 = 0.f;
    for (int j = lo; j < hi; j++) {
        int s = csr_src[j];
        float c0 = expf(lrelu(as[(size_t)s * 2 + 0] + ad0) - m0) * inv0;
        float c1 = expf(lrelu(as[(size_t)s * 2 + 1] + ad1) - m1) * inv1;
        const float* hp = Hf + (size_t)s * 128;
        acc0 = fmaf(hp[lane], c0, acc0);
        acc1 = fmaf(hp[64 + lane], c1, acc1);
    }
    float v0 = acc0 + b[lane];
    float v1 = acc1 + b[64 + lane];
    outp[(size_t)node * 128 + lane]      = v0 > 0.f ? v0 : 0.f;
    outp[(size_t)node * 128 + 64 + lane] = v1 > 0.f ? v1 : 0.f;
}

// layer 2: H=1, one wave per node, lane owns channel (lane)
__global__ void node_agg2_kernel(const int* __restrict__ rowptr, const int* __restrict__ csr_src,
                                 const float* __restrict__ Hf,
                                 const float* __restrict__ as, const float* __restrict__ ad,
                                 const float* __restrict__ b, float* __restrict__ outp) {
    int wave = threadIdx.x >> 6;
    int lane = threadIdx.x & 63;
    int node = blockIdx.x * 4 + wave;
    if (node >= N_NODES) return;
    const int lo = rowptr[node], hi = rowptr[node + 1];
    const float adN = ad[node];

    float m = -INFINITY;
    for (int j = lo + lane; j < hi; j += 64)
        m = fmaxf(m, lrelu(as[csr_src[j]] + adN));
#pragma unroll
    for (int off = 32; off; off >>= 1) m = fmaxf(m, __shfl_xor(m, off));
    float d = 0.f;
    for (int j = lo + lane; j < hi; j += 64)
        d += expf(lrelu(as[csr_src[j]] + adN) - m);
#pragma unroll
    for (int off = 32; off; off >>= 1) d += __shfl_xor(d, off);
    const float inv = 1.f / d;

    float acc = 0.f;
    for (int j = lo; j < hi; j++) {
        int s = csr_src[j];
        float c = expf(lrelu(as[s] + adN) - m) * inv;
        acc = fmaf(Hf[(size_t)s * 64 + lane], c, acc);
    }
    float v = acc + b[lane];
    outp[(size_t)node * 64 + lane] = v > 0.f ? v : 0.f;
}

// ---------- pool + fc + log_softmax ----------
__global__ void pool_fc_kernel(const float* __restrict__ act2,
                               const int* __restrict__ batch,
                               const float* __restrict__ fcW,
                               const float* __restrict__ fcb,
                               float* __restrict__ out) {
    int g = blockIdx.x;
    int c = threadIdx.x;   // 64 threads
    __shared__ int slo, shi;
    if (c == 0) {
        int lo = 0, hi = N_NODES;
        while (lo < hi) { int m = (lo + hi) >> 1; if (batch[m] < g) lo = m + 1; else hi = m; }
        slo = lo;
        lo = 0; hi = N_NODES;
        while (lo < hi) { int m = (lo + hi) >> 1; if (batch[m] < g + 1) lo = m + 1; else hi = m; }
        shi = lo;
    }
    __syncthreads();
    const int lo = slo, hi = shi;
    float sum = 0.f;
    for (int n = lo; n < hi; n++) sum += act2[(size_t)n * HID + c];
    float cnt = (float)(hi - lo);
    __shared__ float ps[HID];
    ps[c] = sum / fmaxf(cnt, 1.f);
    __syncthreads();
    __shared__ float ls[OUT_DIM];
    if (c < OUT_DIM) {
        float l = fcb[c];
#pragma unroll 8
        for (int k = 0; k < HID; k++) l = fmaf(ps[k], fcW[k * OUT_DIM + c], l);
        ls[c] = l;
    }
    __syncthreads();
    if (c < OUT_DIM) {
        float m = fmaxf(ls[0], ls[1]);
        float lse = m + logf(expf(ls[0] - m) + expf(ls[1] - m));
        out[(size_t)g * OUT_DIM + c] = ls[c] - lse;
    }
}

extern "C" void kernel_launch(void* const* d_in, const int* in_sizes, int n_in,
                              void* d_out, int out_size, void* d_ws, size_t ws_size,
                              hipStream_t stream) {
    const float* x    = (const float*)d_in[0];
    const int*   ei   = (const int*)d_in[1];
    const int*   batch= (const int*)d_in[2];
    const float* W1   = (const float*)d_in[3];
    const float* as1w = (const float*)d_in[4];
    const float* ad1w = (const float*)d_in[5];
    const float* b1   = (const float*)d_in[6];
    const float* W2   = (const float*)d_in[7];
    const float* as2w = (const float*)d_in[8];
    const float* ad2w = (const float*)d_in[9];
    const float* b2   = (const float*)d_in[10];
    const float* fcb  = (const float*)d_in[12];
    const float* fcW  = (const float*)d_in[11];

    const size_t N = N_NODES;
    float* ws = (float*)d_ws;
    float* h1    = ws;                        // N*128
    float* act1  = h1   + N * 128;            // N*128
    float* h2    = act1 + N * 128;            // N*64
    float* out2  = h2   + N * 64;             // N*64
    float* alps1 = out2 + N * 64;             // N*2
    float* alpd1 = alps1 + N * 2;             // N*2
    float* alps2 = alpd1 + N * 2;             // N
    float* alpd2 = alps2 + N;                 // N
    int* cnt     = (int*)(alpd2 + N);         // N
    int* rowptr  = cnt + N;                   // N+1
    int* cursor  = rowptr + N + 1;            // N
    int* csr_src = cursor + N;                // EP

    // ---- CSR build (shared by both layers) ----
    hipMemsetAsync(cnt, 0, N * sizeof(int), stream);
    hist_kernel<<<(EP + 255) / 256, 256, 0, stream>>>(ei, cnt);
    scan_kernel<<<1, 1024, 0, stream>>>(cnt, rowptr, cursor);
    scatter_kernel<<<(EP + 255) / 256, 256, 0, stream>>>(ei, cursor, csr_src);

    // ---- layer 1 (H=2) ----
    gemm_nodes<128, 128, 4><<<(N + 3) / 4, 128, 0, stream>>>(x, W1, h1, (int)N);
    alphas_kernel<2><<<(N + 255) / 256, 256, 0, stream>>>(h1, as1w, ad1w, alps1, alpd1, (int)N);
    node_agg1_kernel<<<(N + 3) / 4, 256, 0, stream>>>(rowptr, csr_src, h1, alps1, alpd1, b1, act1);

    // ---- layer 2 (H=1) ----
    gemm_nodes<128, 64, 8><<<(N + 7) / 8, 64, 0, stream>>>(act1, W2, h2, (int)N);
    alphas_kernel<1><<<(N + 255) / 256, 256, 0, stream>>>(h2, as2w, ad2w, alps2, alpd2, (int)N);
    node_agg2_kernel<<<(N + 3) / 4, 256, 0, stream>>>(rowptr, csr_src, h2, alps2, alpd2, b2, out2);

    // ---- pool + fc + log_softmax ----
    pool_fc_kernel<<<N_GRAPHS, 64, 0, stream>>>(out2, batch, fcW, fcb, (float*)d_out);
}

// Round 3
// 485.702 us; speedup vs baseline: 5.3768x; 1.2027x over previous
//
#include <hip/hip_runtime.h>
#include <math.h>

#define N_NODES 50000
#define N_EDGES 800000
#define EP (N_EDGES + N_NODES)   // edges + self loops
#define IN_DIM 128
#define HID 64
#define HEADS 2
#define OUT_DIM 2
#define N_GRAPHS 512
#define NEG_SLOPE 0.2f

// ---------- CSR build ----------
__global__ void hist_kernel(const int* __restrict__ ei, int* __restrict__ cnt) {
    int i = blockIdx.x * blockDim.x + threadIdx.x;
    if (i >= EP) return;
    int d = (i < N_EDGES) ? ei[N_EDGES + i] : (i - N_EDGES);
    atomicAdd(&cnt[d], 1);
}

// single block, 1024 threads, each scans a contiguous chunk of 49 counts
__global__ void scan_kernel(const int* __restrict__ cnt, int* __restrict__ rowptr,
                            int* __restrict__ cursor) {
    const int CHUNK = 49;  // 1024*49 = 50176 >= 50000
    int tid = threadIdx.x;
    int lane = tid & 63, wid = tid >> 6;
    int start = tid * CHUNK;
    int end = start + CHUNK; if (end > N_NODES) end = N_NODES;
    int s = 0;
    for (int i = start; i < end; i++) s += cnt[i];
    // inclusive wave scan of s
    int v = s;
#pragma unroll
    for (int off = 1; off < 64; off <<= 1) {
        int t = __shfl_up(v, off);
        if (lane >= off) v += t;
    }
    __shared__ int wtot[16];
    __shared__ int woff[17];
    if (lane == 63) wtot[wid] = v;
    __syncthreads();
    if (tid == 0) {
        int r = 0;
        for (int w = 0; w < 16; w++) { woff[w] = r; r += wtot[w]; }
        woff[16] = r;
    }
    __syncthreads();
    int run = woff[wid] + v - s;   // exclusive prefix for this thread's chunk
    for (int i = start; i < end; i++) {
        rowptr[i] = run; cursor[i] = run; run += cnt[i];
    }
    if (tid == 1023) rowptr[N_NODES] = woff[16];
}

__global__ void scatter_kernel(const int* __restrict__ ei, int* __restrict__ cursor,
                               int* __restrict__ csr_src) {
    int i = blockIdx.x * blockDim.x + threadIdx.x;
    if (i >= EP) return;
    int s, d;
    if (i < N_EDGES) { s = ei[i]; d = ei[N_EDGES + i]; }
    else             { s = d = i - N_EDGES; }
    int pos = atomicAdd(&cursor[d], 1);
    csr_src[pos] = s;
}

// ---------- dense ----------
template<int K, int COLS, int NPB>
__global__ void gemm_nodes(const float* __restrict__ X, const float* __restrict__ W,
                           float* __restrict__ Y, int n_nodes) {
    __shared__ float xs[NPB][K];
    const int base = blockIdx.x * NPB;
    const int tid = threadIdx.x;
    const float4* X4 = (const float4*)X;
    for (int idx = tid; idx < NPB * (K / 4); idx += COLS) {
        int r = idx / (K / 4), c = idx % (K / 4);
        int n = base + r;
        float4 v = (n < n_nodes) ? X4[(size_t)n * (K / 4) + c] : make_float4(0.f, 0.f, 0.f, 0.f);
        ((float4*)xs[r])[c] = v;
    }
    __syncthreads();
    float acc[NPB];
#pragma unroll
    for (int i = 0; i < NPB; i++) acc[i] = 0.f;
    for (int k = 0; k < K; k++) {
        float w = W[(size_t)k * COLS + tid];
#pragma unroll
        for (int i = 0; i < NPB; i++) acc[i] = fmaf(xs[i][k], w, acc[i]);
    }
#pragma unroll
    for (int i = 0; i < NPB; i++) {
        int n = base + i;
        if (n < n_nodes) Y[(size_t)n * COLS + tid] = acc[i];
    }
}

template<int H>
__global__ void alphas_kernel(const float* __restrict__ Hf,
                              const float* __restrict__ a_src,
                              const float* __restrict__ a_dst,
                              float* __restrict__ as, float* __restrict__ ad, int n) {
    int i = blockIdx.x * blockDim.x + threadIdx.x;
    if (i >= n) return;
#pragma unroll
    for (int h = 0; h < H; h++) {
        const float* hp = Hf + (size_t)i * (H * HID) + h * HID;
        float s = 0.f, d = 0.f;
#pragma unroll 8
        for (int c = 0; c < HID; c++) {
            float v = hp[c];
            s = fmaf(v, a_src[h * HID + c], s);
            d = fmaf(v, a_dst[h * HID + c], d);
        }
        as[(size_t)i * H + h] = s;
        ad[(size_t)i * H + h] = d;
    }
}

__device__ __forceinline__ float lrelu(float e) { return e > 0.f ? e : NEG_SLOPE * e; }

// ---------- fused per-node softmax + aggregate + bias + relu ----------
// layer 1: H=2. pass1: lane-parallel exp + denom (stores unnormalized ex);
// pass2: serial edge walk, unit work = 2 loads + 2 FMA; normalize at end.
__global__ void node_agg1_kernel(const int* __restrict__ rowptr, const int* __restrict__ csr_src,
                                 const float* __restrict__ Hf,
                                 const float* __restrict__ as, const float* __restrict__ ad,
                                 const float* __restrict__ b, float* __restrict__ outp,
                                 float* __restrict__ exbuf) {
    int wave = threadIdx.x >> 6;
    int lane = threadIdx.x & 63;
    int node = blockIdx.x * 4 + wave;
    if (node >= N_NODES) return;
    const int lo = rowptr[node], hi = rowptr[node + 1];
    const float ad0 = ad[(size_t)node * 2 + 0], ad1 = ad[(size_t)node * 2 + 1];

    float d0 = 0.f, d1 = 0.f;
    for (int j = lo + lane; j < hi; j += 64) {
        int s = csr_src[j];
        float2 a = *(const float2*)&as[(size_t)s * 2];
        float ex0 = __expf(lrelu(a.x + ad0));
        float ex1 = __expf(lrelu(a.y + ad1));
        *(float2*)&exbuf[(size_t)j * 2] = make_float2(ex0, ex1);
        d0 += ex0; d1 += ex1;
    }
#pragma unroll
    for (int off = 32; off; off >>= 1) {
        d0 += __shfl_xor(d0, off);
        d1 += __shfl_xor(d1, off);
    }
    const float inv0 = 1.f / d0, inv1 = 1.f / d1;

    float acc0 = 0.f, acc1 = 0.f;
    int j = lo;
    for (; j + 4 <= hi; j += 4) {
        int s0 = csr_src[j + 0], s1 = csr_src[j + 1];
        int s2 = csr_src[j + 2], s3 = csr_src[j + 3];
        float2 e0 = *(const float2*)&exbuf[(size_t)(j + 0) * 2];
        float2 e1 = *(const float2*)&exbuf[(size_t)(j + 1) * 2];
        float2 e2 = *(const float2*)&exbuf[(size_t)(j + 2) * 2];
        float2 e3 = *(const float2*)&exbuf[(size_t)(j + 3) * 2];
        const float* h0 = Hf + (size_t)s0 * 128;
        const float* h1p = Hf + (size_t)s1 * 128;
        const float* h2p = Hf + (size_t)s2 * 128;
        const float* h3p = Hf + (size_t)s3 * 128;
        acc0 = fmaf(h0[lane], e0.x, acc0);  acc1 = fmaf(h0[64 + lane], e0.y, acc1);
        acc0 = fmaf(h1p[lane], e1.x, acc0); acc1 = fmaf(h1p[64 + lane], e1.y, acc1);
        acc0 = fmaf(h2p[lane], e2.x, acc0); acc1 = fmaf(h2p[64 + lane], e2.y, acc1);
        acc0 = fmaf(h3p[lane], e3.x, acc0); acc1 = fmaf(h3p[64 + lane], e3.y, acc1);
    }
    for (; j < hi; j++) {
        int s = csr_src[j];
        float2 e = *(const float2*)&exbuf[(size_t)j * 2];
        const float* hp = Hf + (size_t)s * 128;
        acc0 = fmaf(hp[lane], e.x, acc0);
        acc1 = fmaf(hp[64 + lane], e.y, acc1);
    }
    float v0 = acc0 * inv0 + b[lane];
    float v1 = acc1 * inv1 + b[64 + lane];
    outp[(size_t)node * 128 + lane]      = v0 > 0.f ? v0 : 0.f;
    outp[(size_t)node * 128 + 64 + lane] = v1 > 0.f ? v1 : 0.f;
}

// layer 2: H=1
__global__ void node_agg2_kernel(const int* __restrict__ rowptr, const int* __restrict__ csr_src,
                                 const float* __restrict__ Hf,
                                 const float* __restrict__ as, const float* __restrict__ ad,
                                 const float* __restrict__ b, float* __restrict__ outp,
                                 float* __restrict__ exbuf) {
    int wave = threadIdx.x >> 6;
    int lane = threadIdx.x & 63;
    int node = blockIdx.x * 4 + wave;
    if (node >= N_NODES) return;
    const int lo = rowptr[node], hi = rowptr[node + 1];
    const float adN = ad[node];

    float d = 0.f;
    for (int j = lo + lane; j < hi; j += 64) {
        float ex = __expf(lrelu(as[csr_src[j]] + adN));
        exbuf[j] = ex;
        d += ex;
    }
#pragma unroll
    for (int off = 32; off; off >>= 1) d += __shfl_xor(d, off);
    const float inv = 1.f / d;

    float acc = 0.f;
    int j = lo;
    for (; j + 4 <= hi; j += 4) {
        int s0 = csr_src[j + 0], s1 = csr_src[j + 1];
        int s2 = csr_src[j + 2], s3 = csr_src[j + 3];
        float e0 = exbuf[j + 0], e1 = exbuf[j + 1];
        float e2 = exbuf[j + 2], e3 = exbuf[j + 3];
        acc = fmaf(Hf[(size_t)s0 * 64 + lane], e0, acc);
        acc = fmaf(Hf[(size_t)s1 * 64 + lane], e1, acc);
        acc = fmaf(Hf[(size_t)s2 * 64 + lane], e2, acc);
        acc = fmaf(Hf[(size_t)s3 * 64 + lane], e3, acc);
    }
    for (; j < hi; j++)
        acc = fmaf(Hf[(size_t)csr_src[j] * 64 + lane], exbuf[j], acc);
    float v = acc * inv + b[lane];
    outp[(size_t)node * 64 + lane] = v > 0.f ? v : 0.f;
}

// ---------- pool + fc + log_softmax: 4 waves per graph ----------
__global__ void pool_fc_kernel(const float* __restrict__ act2,
                               const int* __restrict__ batch,
                               const float* __restrict__ fcW,
                               const float* __restrict__ fcb,
                               float* __restrict__ out) {
    int g = blockIdx.x;
    int tid = threadIdx.x;            // 256
    int wid = tid >> 6, c = tid & 63;
    __shared__ int slo, shi;
    if (tid == 0) {
        int lo = 0, hi = N_NODES;
        while (lo < hi) { int m = (lo + hi) >> 1; if (batch[m] < g) lo = m + 1; else hi = m; }
        slo = lo;
        lo = 0; hi = N_NODES;
        while (lo < hi) { int m = (lo + hi) >> 1; if (batch[m] < g + 1) lo = m + 1; else hi = m; }
        shi = lo;
    }
    __syncthreads();
    const int lo = slo, hi = shi;
    float sum = 0.f;
    for (int n = lo + wid; n < hi; n += 4) sum += act2[(size_t)n * HID + c];
    __shared__ float ps[4][HID];
    ps[wid][c] = sum;
    __syncthreads();
    if (wid == 0) {
        float t = ps[0][c] + ps[1][c] + ps[2][c] + ps[3][c];
        float cnt = (float)(hi - lo);
        __shared__ float pooled[HID];
        pooled[c] = t / fmaxf(cnt, 1.f);
        __syncthreads();
        __shared__ float ls[OUT_DIM];
        if (c < OUT_DIM) {
            float l = fcb[c];
#pragma unroll 8
            for (int k = 0; k < HID; k++) l = fmaf(pooled[k], fcW[k * OUT_DIM + c], l);
            ls[c] = l;
        }
        __syncthreads();
        if (c < OUT_DIM) {
            float m = fmaxf(ls[0], ls[1]);
            float lse = m + logf(expf(ls[0] - m) + expf(ls[1] - m));
            out[(size_t)g * OUT_DIM + c] = ls[c] - lse;
        }
    }
}

extern "C" void kernel_launch(void* const* d_in, const int* in_sizes, int n_in,
                              void* d_out, int out_size, void* d_ws, size_t ws_size,
                              hipStream_t stream) {
    const float* x    = (const float*)d_in[0];
    const int*   ei   = (const int*)d_in[1];
    const int*   batch= (const int*)d_in[2];
    const float* W1   = (const float*)d_in[3];
    const float* as1w = (const float*)d_in[4];
    const float* ad1w = (const float*)d_in[5];
    const float* b1   = (const float*)d_in[6];
    const float* W2   = (const float*)d_in[7];
    const float* as2w = (const float*)d_in[8];
    const float* ad2w = (const float*)d_in[9];
    const float* b2   = (const float*)d_in[10];
    const float* fcW  = (const float*)d_in[11];
    const float* fcb  = (const float*)d_in[12];

    const size_t N = N_NODES;
    float* ws = (float*)d_ws;
    float* h1    = ws;                        // N*128
    float* act1  = h1   + N * 128;            // N*128
    float* h2    = act1 + N * 128;            // N*64
    float* out2  = h2   + N * 64;             // N*64
    float* alps1 = out2 + N * 64;             // N*2
    float* alpd1 = alps1 + N * 2;             // N*2
    float* alps2 = alpd1 + N * 2;             // N
    float* alpd2 = alps2 + N;                 // N
    int* cnt     = (int*)(alpd2 + N);         // N
    int* rowptr  = cnt + N;                   // N+1
    int* cursor  = rowptr + N + 1;            // N
    int* csr_src = cursor + N;                // EP
    float* exbuf = (float*)(csr_src + EP);    // EP*2

    // ---- CSR build (shared by both layers) ----
    hipMemsetAsync(cnt, 0, N * sizeof(int), stream);
    hist_kernel<<<(EP + 255) / 256, 256, 0, stream>>>(ei, cnt);
    scan_kernel<<<1, 1024, 0, stream>>>(cnt, rowptr, cursor);
    scatter_kernel<<<(EP + 255) / 256, 256, 0, stream>>>(ei, cursor, csr_src);

    // ---- layer 1 (H=2) ----
    gemm_nodes<128, 128, 4><<<(N + 3) / 4, 128, 0, stream>>>(x, W1, h1, (int)N);
    alphas_kernel<2><<<(N + 255) / 256, 256, 0, stream>>>(h1, as1w, ad1w, alps1, alpd1, (int)N);
    node_agg1_kernel<<<(N + 3) / 4, 256, 0, stream>>>(rowptr, csr_src, h1, alps1, alpd1, b1, act1, exbuf);

    // ---- layer 2 (H=1) ----
    gemm_nodes<128, 64, 8><<<(N + 7) / 8, 64, 0, stream>>>(act1, W2, h2, (int)N);
    alphas_kernel<1><<<(N + 255) / 256, 256, 0, stream>>>(h2, as2w, ad2w, alps2, alpd2, (int)N);
    node_agg2_kernel<<<(N + 3) / 4, 256, 0, stream>>>(rowptr, csr_src, h2, alps2, alpd2, b2, out2, exbuf);

    // ---- pool + fc + log_softmax ----
    pool_fc_kernel<<<N_GRAPHS, 256, 0, stream>>>(out2, batch, fcW, fcb, (float*)d_out);
}

// Round 6
// 383.636 us; speedup vs baseline: 6.8073x; 1.2660x over previous
//
#include <hip/hip_runtime.h>
#include <math.h>

#define N_NODES 50000
#define N_EDGES 800000
#define EP (N_EDGES + N_NODES)   // edges + self loops
#define IN_DIM 128
#define HID 64
#define HEADS 2
#define OUT_DIM 2
#define N_GRAPHS 512
#define NEG_SLOPE 0.2f
#define NB_SCAN 196              // ceil(50000/256)

// ---------- CSR build ----------
__global__ void hist_kernel(const int* __restrict__ ei, int* __restrict__ cnt) {
    int i = blockIdx.x * blockDim.x + threadIdx.x;
    if (i >= EP) return;
    int d = (i < N_EDGES) ? ei[N_EDGES + i] : (i - N_EDGES);
    atomicAdd(&cnt[d], 1);
}

// 1) per-block sums of cnt
__global__ void partial_kernel(const int* __restrict__ cnt, int* __restrict__ bsum) {
    int tid = threadIdx.x;
    int i = blockIdx.x * 256 + tid;
    int lane = tid & 63, wid = tid >> 6;
    int v = (i < N_NODES) ? cnt[i] : 0;
#pragma unroll
    for (int off = 32; off; off >>= 1) v += __shfl_xor(v, off);
    __shared__ int wsum[4];
    if (lane == 0) wsum[wid] = v;
    __syncthreads();
    if (tid == 0) bsum[blockIdx.x] = wsum[0] + wsum[1] + wsum[2] + wsum[3];
}

// 2) scan the 196 block sums -> exclusive block offsets, write rowptr[N]
__global__ void scanb_kernel(const int* __restrict__ bsum, int* __restrict__ boff,
                             int* __restrict__ rowptr) {
    int tid = threadIdx.x;          // 256
    int lane = tid & 63, wid = tid >> 6;
    int v = (tid < NB_SCAN) ? bsum[tid] : 0;
    int incl = v;
#pragma unroll
    for (int off = 1; off < 64; off <<= 1) {
        int t = __shfl_up(incl, off);
        if (lane >= off) incl += t;
    }
    __shared__ int wt[4];
    if (lane == 63) wt[wid] = incl;
    __syncthreads();
    int add = 0;
    for (int w = 0; w < wid; w++) add += wt[w];
    incl += add;
    if (tid < NB_SCAN) boff[tid] = incl - v;
    if (tid == NB_SCAN - 1) rowptr[N_NODES] = incl;
}

// 3) block-level exclusive scan of cnt + block offset -> rowptr, cursor
__global__ void scanc_kernel(const int* __restrict__ cnt, const int* __restrict__ boff,
                             int* __restrict__ rowptr, int* __restrict__ cursor) {
    int tid = threadIdx.x;
    int i = blockIdx.x * 256 + tid;
    int lane = tid & 63, wid = tid >> 6;
    int v = (i < N_NODES) ? cnt[i] : 0;
    int incl = v;
#pragma unroll
    for (int off = 1; off < 64; off <<= 1) {
        int t = __shfl_up(incl, off);
        if (lane >= off) incl += t;
    }
    __shared__ int wt[4];
    if (lane == 63) wt[wid] = incl;
    __syncthreads();
    int add = boff[blockIdx.x];
    for (int w = 0; w < wid; w++) add += wt[w];
    int excl = add + incl - v;
    if (i < N_NODES) { rowptr[i] = excl; cursor[i] = excl; }
}

__global__ void scatter_kernel(const int* __restrict__ ei, int* __restrict__ cursor,
                               int* __restrict__ csr_src) {
    int i = blockIdx.x * blockDim.x + threadIdx.x;
    if (i >= EP) return;
    int s, d;
    if (i < N_EDGES) { s = ei[i]; d = ei[N_EDGES + i]; }
    else             { s = d = i - N_EDGES; }
    int pos = atomicAdd(&cursor[d], 1);
    csr_src[pos] = s;
}

// ---------- dense ----------
template<int K, int COLS, int NPB>
__global__ void gemm_nodes(const float* __restrict__ X, const float* __restrict__ W,
                           float* __restrict__ Y, int n_nodes) {
    __shared__ float xs[NPB][K];
    const int base = blockIdx.x * NPB;
    const int tid = threadIdx.x;
    const float4* X4 = (const float4*)X;
    for (int idx = tid; idx < NPB * (K / 4); idx += COLS) {
        int r = idx / (K / 4), c = idx % (K / 4);
        int n = base + r;
        float4 v = (n < n_nodes) ? X4[(size_t)n * (K / 4) + c] : make_float4(0.f, 0.f, 0.f, 0.f);
        ((float4*)xs[r])[c] = v;
    }
    __syncthreads();
    float acc[NPB];
#pragma unroll
    for (int i = 0; i < NPB; i++) acc[i] = 0.f;
    for (int k = 0; k < K; k++) {
        float w = W[(size_t)k * COLS + tid];
#pragma unroll
        for (int i = 0; i < NPB; i++) acc[i] = fmaf(xs[i][k], w, acc[i]);
    }
#pragma unroll
    for (int i = 0; i < NPB; i++) {
        int n = base + i;
        if (n < n_nodes) Y[(size_t)n * COLS + tid] = acc[i];
    }
}

template<int H>
__global__ void alphas_kernel(const float* __restrict__ Hf,
                              const float* __restrict__ a_src,
                              const float* __restrict__ a_dst,
                              float* __restrict__ as, float* __restrict__ ad, int n) {
    int i = blockIdx.x * blockDim.x + threadIdx.x;
    if (i >= n) return;
#pragma unroll
    for (int h = 0; h < H; h++) {
        const float* hp = Hf + (size_t)i * (H * HID) + h * HID;
        float s = 0.f, d = 0.f;
#pragma unroll 8
        for (int c = 0; c < HID; c++) {
            float v = hp[c];
            s = fmaf(v, a_src[h * HID + c], s);
            d = fmaf(v, a_dst[h * HID + c], d);
        }
        as[(size_t)i * H + h] = s;
        ad[(size_t)i * H + h] = d;
    }
}

__device__ __forceinline__ float lrelu(float e) { return e > 0.f ? e : NEG_SLOPE * e; }

// ---------- fused per-node softmax + aggregate + bias + relu ----------
__global__ void node_agg1_kernel(const int* __restrict__ rowptr, const int* __restrict__ csr_src,
                                 const float* __restrict__ Hf,
                                 const float* __restrict__ as, const float* __restrict__ ad,
                                 const float* __restrict__ b, float* __restrict__ outp,
                                 float* __restrict__ exbuf) {
    int wave = threadIdx.x >> 6;
    int lane = threadIdx.x & 63;
    int node = blockIdx.x * 4 + wave;
    if (node >= N_NODES) return;
    const int lo = rowptr[node], hi = rowptr[node + 1];
    const float ad0 = ad[(size_t)node * 2 + 0], ad1 = ad[(size_t)node * 2 + 1];

    float d0 = 0.f, d1 = 0.f;
    for (int j = lo + lane; j < hi; j += 64) {
        int s = csr_src[j];
        float2 a = *(const float2*)&as[(size_t)s * 2];
        float ex0 = __expf(lrelu(a.x + ad0));
        float ex1 = __expf(lrelu(a.y + ad1));
        *(float2*)&exbuf[(size_t)j * 2] = make_float2(ex0, ex1);
        d0 += ex0; d1 += ex1;
    }
#pragma unroll
    for (int off = 32; off; off >>= 1) {
        d0 += __shfl_xor(d0, off);
        d1 += __shfl_xor(d1, off);
    }
    const float inv0 = 1.f / d0, inv1 = 1.f / d1;

    float acc0 = 0.f, acc1 = 0.f;
    int j = lo;
    for (; j + 4 <= hi; j += 4) {
        int s0 = csr_src[j + 0], s1 = csr_src[j + 1];
        int s2 = csr_src[j + 2], s3 = csr_src[j + 3];
        float2 e0 = *(const float2*)&exbuf[(size_t)(j + 0) * 2];
        float2 e1 = *(const float2*)&exbuf[(size_t)(j + 1) * 2];
        float2 e2 = *(const float2*)&exbuf[(size_t)(j + 2) * 2];
        float2 e3 = *(const float2*)&exbuf[(size_t)(j + 3) * 2];
        const float* h0 = Hf + (size_t)s0 * 128;
        const float* h1p = Hf + (size_t)s1 * 128;
        const float* h2p = Hf + (size_t)s2 * 128;
        const float* h3p = Hf + (size_t)s3 * 128;
        acc0 = fmaf(h0[lane], e0.x, acc0);  acc1 = fmaf(h0[64 + lane], e0.y, acc1);
        acc0 = fmaf(h1p[lane], e1.x, acc0); acc1 = fmaf(h1p[64 + lane], e1.y, acc1);
        acc0 = fmaf(h2p[lane], e2.x, acc0); acc1 = fmaf(h2p[64 + lane], e2.y, acc1);
        acc0 = fmaf(h3p[lane], e3.x, acc0); acc1 = fmaf(h3p[64 + lane], e3.y, acc1);
    }
    for (; j < hi; j++) {
        int s = csr_src[j];
        float2 e = *(const float2*)&exbuf[(size_t)j * 2];
        const float* hp = Hf + (size_t)s * 128;
        acc0 = fmaf(hp[lane], e.x, acc0);
        acc1 = fmaf(hp[64 + lane], e.y, acc1);
    }
    float v0 = acc0 * inv0 + b[lane];
    float v1 = acc1 * inv1 + b[64 + lane];
    outp[(size_t)node * 128 + lane]      = v0 > 0.f ? v0 : 0.f;
    outp[(size_t)node * 128 + 64 + lane] = v1 > 0.f ? v1 : 0.f;
}

__global__ void node_agg2_kernel(const int* __restrict__ rowptr, const int* __restrict__ csr_src,
                                 const float* __restrict__ Hf,
                                 const float* __restrict__ as, const float* __restrict__ ad,
                                 const float* __restrict__ b, float* __restrict__ outp,
                                 float* __restrict__ exbuf) {
    int wave = threadIdx.x >> 6;
    int lane = threadIdx.x & 63;
    int node = blockIdx.x * 4 + wave;
    if (node >= N_NODES) return;
    const int lo = rowptr[node], hi = rowptr[node + 1];
    const float adN = ad[node];

    float d = 0.f;
    for (int j = lo + lane; j < hi; j += 64) {
        float ex = __expf(lrelu(as[csr_src[j]] + adN));
        exbuf[j] = ex;
        d += ex;
    }
#pragma unroll
    for (int off = 32; off; off >>= 1) d += __shfl_xor(d, off);
    const float inv = 1.f / d;

    float acc = 0.f;
    int j = lo;
    for (; j + 4 <= hi; j += 4) {
        int s0 = csr_src[j + 0], s1 = csr_src[j + 1];
        int s2 = csr_src[j + 2], s3 = csr_src[j + 3];
        float e0 = exbuf[j + 0], e1 = exbuf[j + 1];
        float e2 = exbuf[j + 2], e3 = exbuf[j + 3];
        acc = fmaf(Hf[(size_t)s0 * 64 + lane], e0, acc);
        acc = fmaf(Hf[(size_t)s1 * 64 + lane], e1, acc);
        acc = fmaf(Hf[(size_t)s2 * 64 + lane], e2, acc);
        acc = fmaf(Hf[(size_t)s3 * 64 + lane], e3, acc);
    }
    for (; j < hi; j++)
        acc = fmaf(Hf[(size_t)csr_src[j] * 64 + lane], exbuf[j], acc);
    float v = acc * inv + b[lane];
    outp[(size_t)node * 64 + lane] = v > 0.f ? v : 0.f;
}

// ---------- pool + fc + log_softmax: 4 waves per graph ----------
__global__ void pool_fc_kernel(const float* __restrict__ act2,
                               const int* __restrict__ batch,
                               const float* __restrict__ fcW,
                               const float* __restrict__ fcb,
                               float* __restrict__ out) {
    int g = blockIdx.x;
    int tid = threadIdx.x;            // 256
    int wid = tid >> 6, c = tid & 63;
    __shared__ int slo, shi;
    if (tid == 0) {
        int lo = 0, hi = N_NODES;
        while (lo < hi) { int m = (lo + hi) >> 1; if (batch[m] < g) lo = m + 1; else hi = m; }
        slo = lo;
        lo = 0; hi = N_NODES;
        while (lo < hi) { int m = (lo + hi) >> 1; if (batch[m] < g + 1) lo = m + 1; else hi = m; }
        shi = lo;
    }
    __syncthreads();
    const int lo = slo, hi = shi;
    float sum = 0.f;
    for (int n = lo + wid; n < hi; n += 4) sum += act2[(size_t)n * HID + c];
    __shared__ float ps[4][HID];
    ps[wid][c] = sum;
    __syncthreads();
    if (wid == 0) {
        float t = ps[0][c] + ps[1][c] + ps[2][c] + ps[3][c];
        float cnt = (float)(hi - lo);
        __shared__ float pooled[HID];
        pooled[c] = t / fmaxf(cnt, 1.f);
        __syncthreads();
        __shared__ float ls[OUT_DIM];
        if (c < OUT_DIM) {
            float l = fcb[c];
#pragma unroll 8
            for (int k = 0; k < HID; k++) l = fmaf(pooled[k], fcW[k * OUT_DIM + c], l);
            ls[c] = l;
        }
        __syncthreads();
        if (c < OUT_DIM) {
            float m = fmaxf(ls[0], ls[1]);
            float lse = m + logf(expf(ls[0] - m) + expf(ls[1] - m));
            out[(size_t)g * OUT_DIM + c] = ls[c] - lse;
        }
    }
}

extern "C" void kernel_launch(void* const* d_in, const int* in_sizes, int n_in,
                              void* d_out, int out_size, void* d_ws, size_t ws_size,
                              hipStream_t stream) {
    const float* x    = (const float*)d_in[0];
    const int*   ei   = (const int*)d_in[1];
    const int*   batch= (const int*)d_in[2];
    const float* W1   = (const float*)d_in[3];
    const float* as1w = (const float*)d_in[4];
    const float* ad1w = (const float*)d_in[5];
    const float* b1   = (const float*)d_in[6];
    const float* W2   = (const float*)d_in[7];
    const float* as2w = (const float*)d_in[8];
    const float* ad2w = (const float*)d_in[9];
    const float* b2   = (const float*)d_in[10];
    const float* fcW  = (const float*)d_in[11];
    const float* fcb  = (const float*)d_in[12];

    const size_t N = N_NODES;
    float* ws = (float*)d_ws;
    float* h1    = ws;                        // N*128
    float* act1  = h1   + N * 128;            // N*128
    float* h2    = act1 + N * 128;            // N*64
    float* out2  = h2   + N * 64;             // N*64
    float* alps1 = out2 + N * 64;             // N*2
    float* alpd1 = alps1 + N * 2;             // N*2
    float* alps2 = alpd1 + N * 2;             // N
    float* alpd2 = alps2 + N;                 // N
    int* cnt     = (int*)(alpd2 + N);         // N
    int* rowptr  = cnt + N;                   // N+1
    int* cursor  = rowptr + N + 1;            // N
    int* bsum    = cursor + N;                // NB_SCAN
    int* boff    = bsum + NB_SCAN;            // NB_SCAN
    int* csr_src = boff + NB_SCAN;            // EP
    float* exbuf = (float*)(csr_src + EP);    // EP*2

    // ---- CSR build (shared by both layers) ----
    hipMemsetAsync(cnt, 0, N * sizeof(int), stream);
    hist_kernel<<<(EP + 255) / 256, 256, 0, stream>>>(ei, cnt);
    partial_kernel<<<NB_SCAN, 256, 0, stream>>>(cnt, bsum);
    scanb_kernel<<<1, 256, 0, stream>>>(bsum, boff, rowptr);
    scanc_kernel<<<NB_SCAN, 256, 0, stream>>>(cnt, boff, rowptr, cursor);
    scatter_kernel<<<(EP + 255) / 256, 256, 0, stream>>>(ei, cursor, csr_src);

    // ---- layer 1 (H=2) ----
    gemm_nodes<128, 128, 4><<<(N + 3) / 4, 128, 0, stream>>>(x, W1, h1, (int)N);
    alphas_kernel<2><<<(N + 255) / 256, 256, 0, stream>>>(h1, as1w, ad1w, alps1, alpd1, (int)N);
    node_agg1_kernel<<<(N + 3) / 4, 256, 0, stream>>>(rowptr, csr_src, h1, alps1, alpd1, b1, act1, exbuf);

    // ---- layer 2 (H=1) ----
    gemm_nodes<128, 64, 8><<<(N + 7) / 8, 64, 0, stream>>>(act1, W2, h2, (int)N);
    alphas_kernel<1><<<(N + 255) / 256, 256, 0, stream>>>(h2, as2w, ad2w, alps2, alpd2, (int)N);
    node_agg2_kernel<<<(N + 3) / 4, 256, 0, stream>>>(rowptr, csr_src, h2, alps2, alpd2, b2, out2, exbuf);

    // ---- pool + fc + log_softmax ----
    pool_fc_kernel<<<N_GRAPHS, 256, 0, stream>>>(out2, batch, fcW, fcb, (float*)d_out);
}

// Round 7
// 355.483 us; speedup vs baseline: 7.3464x; 1.0792x over previous
//
#include <hip/hip_runtime.h>
#include <math.h>

#define N_NODES 50000
#define N_EDGES 800000
#define EP (N_EDGES + N_NODES)   // edges + self loops
#define IN_DIM 128
#define HID 64
#define HEADS 2
#define OUT_DIM 2
#define N_GRAPHS 512
#define NEG_SLOPE 0.2f
#define NB_SCAN 196              // ceil(50000/256)

typedef unsigned int uint;
typedef unsigned short ushort;

// round-to-nearest-even f32 -> bf16
__device__ __forceinline__ ushort f2bf(float f) {
    uint u = __float_as_uint(f);
    u += 0x7fffu + ((u >> 16) & 1u);
    return (ushort)(u >> 16);
}
__device__ __forceinline__ float bf_lo(uint u) { return __uint_as_float(u << 16); }
__device__ __forceinline__ float bf_hi(uint u) { return __uint_as_float(u & 0xffff0000u); }

// ---------- CSR build ----------
__global__ void hist_kernel(const int* __restrict__ ei, int* __restrict__ cnt) {
    int i = blockIdx.x * blockDim.x + threadIdx.x;
    if (i >= EP) return;
    int d = (i < N_EDGES) ? ei[N_EDGES + i] : (i - N_EDGES);
    atomicAdd(&cnt[d], 1);
}

__global__ void partial_kernel(const int* __restrict__ cnt, int* __restrict__ bsum) {
    int tid = threadIdx.x;
    int i = blockIdx.x * 256 + tid;
    int lane = tid & 63, wid = tid >> 6;
    int v = (i < N_NODES) ? cnt[i] : 0;
#pragma unroll
    for (int off = 32; off; off >>= 1) v += __shfl_xor(v, off);
    __shared__ int wsum[4];
    if (lane == 0) wsum[wid] = v;
    __syncthreads();
    if (tid == 0) bsum[blockIdx.x] = wsum[0] + wsum[1] + wsum[2] + wsum[3];
}

__global__ void scanb_kernel(const int* __restrict__ bsum, int* __restrict__ boff,
                             int* __restrict__ rowptr) {
    int tid = threadIdx.x;          // 256
    int lane = tid & 63, wid = tid >> 6;
    int v = (tid < NB_SCAN) ? bsum[tid] : 0;
    int incl = v;
#pragma unroll
    for (int off = 1; off < 64; off <<= 1) {
        int t = __shfl_up(incl, off);
        if (lane >= off) incl += t;
    }
    __shared__ int wt[4];
    if (lane == 63) wt[wid] = incl;
    __syncthreads();
    int add = 0;
    for (int w = 0; w < wid; w++) add += wt[w];
    incl += add;
    if (tid < NB_SCAN) boff[tid] = incl - v;
    if (tid == NB_SCAN - 1) rowptr[N_NODES] = incl;
}

__global__ void scanc_kernel(const int* __restrict__ cnt, const int* __restrict__ boff,
                             int* __restrict__ rowptr, int* __restrict__ cursor) {
    int tid = threadIdx.x;
    int i = blockIdx.x * 256 + tid;
    int lane = tid & 63, wid = tid >> 6;
    int v = (i < N_NODES) ? cnt[i] : 0;
    int incl = v;
#pragma unroll
    for (int off = 1; off < 64; off <<= 1) {
        int t = __shfl_up(incl, off);
        if (lane >= off) incl += t;
    }
    __shared__ int wt[4];
    if (lane == 63) wt[wid] = incl;
    __syncthreads();
    int add = boff[blockIdx.x];
    for (int w = 0; w < wid; w++) add += wt[w];
    int excl = add + incl - v;
    if (i < N_NODES) { rowptr[i] = excl; cursor[i] = excl; }
}

__global__ void scatter_kernel(const int* __restrict__ ei, int* __restrict__ cursor,
                               int* __restrict__ csr_src) {
    int i = blockIdx.x * blockDim.x + threadIdx.x;
    if (i >= EP) return;
    int s, d;
    if (i < N_EDGES) { s = ei[i]; d = ei[N_EDGES + i]; }
    else             { s = d = i - N_EDGES; }
    int pos = atomicAdd(&cursor[d], 1);
    csr_src[pos] = s;
}

// ---------- dense: fp32 in, bf16 out ----------
template<int K, int COLS, int NPB>
__global__ void gemm_nodes(const float* __restrict__ X, const float* __restrict__ W,
                           ushort* __restrict__ Y, int n_nodes) {
    __shared__ float xs[NPB][K];
    const int base = blockIdx.x * NPB;
    const int tid = threadIdx.x;
    const float4* X4 = (const float4*)X;
    for (int idx = tid; idx < NPB * (K / 4); idx += COLS) {
        int r = idx / (K / 4), c = idx % (K / 4);
        int n = base + r;
        float4 v = (n < n_nodes) ? X4[(size_t)n * (K / 4) + c] : make_float4(0.f, 0.f, 0.f, 0.f);
        ((float4*)xs[r])[c] = v;
    }
    __syncthreads();
    float acc[NPB];
#pragma unroll
    for (int i = 0; i < NPB; i++) acc[i] = 0.f;
    for (int k = 0; k < K; k++) {
        float w = W[(size_t)k * COLS + tid];
#pragma unroll
        for (int i = 0; i < NPB; i++) acc[i] = fmaf(xs[i][k], w, acc[i]);
    }
#pragma unroll
    for (int i = 0; i < NPB; i++) {
        int n = base + i;
        if (n < n_nodes) Y[(size_t)n * COLS + tid] = f2bf(acc[i]);
    }
}

// per-node attention logits from bf16 h (uint = 2 channels)
template<int H>
__global__ void alphas_kernel(const uint* __restrict__ Hb,
                              const float* __restrict__ a_src,
                              const float* __restrict__ a_dst,
                              float* __restrict__ as, float* __restrict__ ad, int n) {
    int i = blockIdx.x * blockDim.x + threadIdx.x;
    if (i >= n) return;
    const uint* hp = Hb + (size_t)i * (H * 32);
#pragma unroll
    for (int h = 0; h < H; h++) {
        float s = 0.f, d = 0.f;
#pragma unroll 8
        for (int j = 0; j < 32; j++) {
            uint u = hp[h * 32 + j];
            float v0 = bf_lo(u), v1 = bf_hi(u);
            s = fmaf(v0, a_src[h * 64 + 2 * j], s);
            s = fmaf(v1, a_src[h * 64 + 2 * j + 1], s);
            d = fmaf(v0, a_dst[h * 64 + 2 * j], d);
            d = fmaf(v1, a_dst[h * 64 + 2 * j + 1], d);
        }
        as[(size_t)i * H + h] = s;
        ad[(size_t)i * H + h] = d;
    }
}

__device__ __forceinline__ float lrelu(float e) { return e > 0.f ? e : NEG_SLOPE * e; }

// ---------- fused per-node softmax + aggregate + bias + relu ----------
// layer 1: H=2; lane owns channels (2*lane, 2*lane+1) -> same head per lane
__global__ void node_agg1_kernel(const int* __restrict__ rowptr, const int* __restrict__ csr_src,
                                 const uint* __restrict__ Hb,
                                 const float* __restrict__ as, const float* __restrict__ ad,
                                 const float* __restrict__ b, float* __restrict__ outp,
                                 float* __restrict__ exbuf) {
    int wave = threadIdx.x >> 6;
    int lane = threadIdx.x & 63;
    int node = blockIdx.x * 4 + wave;
    if (node >= N_NODES) return;
    const int lo = rowptr[node], hi = rowptr[node + 1];
    const float ad0 = ad[(size_t)node * 2 + 0], ad1 = ad[(size_t)node * 2 + 1];

    float d0 = 0.f, d1 = 0.f;
    for (int j = lo + lane; j < hi; j += 64) {
        int s = csr_src[j];
        float2 a = *(const float2*)&as[(size_t)s * 2];
        float ex0 = __expf(lrelu(a.x + ad0));
        float ex1 = __expf(lrelu(a.y + ad1));
        *(float2*)&exbuf[(size_t)j * 2] = make_float2(ex0, ex1);
        d0 += ex0; d1 += ex1;
    }
#pragma unroll
    for (int off = 32; off; off >>= 1) {
        d0 += __shfl_xor(d0, off);
        d1 += __shfl_xor(d1, off);
    }
    const float inv = (lane < 32) ? (1.f / d0) : (1.f / d1);

    float acc0 = 0.f, acc1 = 0.f;
    int j = lo;
    for (; j + 4 <= hi; j += 4) {
        int s0 = csr_src[j + 0], s1 = csr_src[j + 1];
        int s2 = csr_src[j + 2], s3 = csr_src[j + 3];
        float2 e0 = *(const float2*)&exbuf[(size_t)(j + 0) * 2];
        float2 e1 = *(const float2*)&exbuf[(size_t)(j + 1) * 2];
        float2 e2 = *(const float2*)&exbuf[(size_t)(j + 2) * 2];
        float2 e3 = *(const float2*)&exbuf[(size_t)(j + 3) * 2];
        uint u0 = Hb[(size_t)s0 * 64 + lane];
        uint u1 = Hb[(size_t)s1 * 64 + lane];
        uint u2 = Hb[(size_t)s2 * 64 + lane];
        uint u3 = Hb[(size_t)s3 * 64 + lane];
        float c0 = (lane < 32) ? e0.x : e0.y;
        float c1 = (lane < 32) ? e1.x : e1.y;
        float c2 = (lane < 32) ? e2.x : e2.y;
        float c3 = (lane < 32) ? e3.x : e3.y;
        acc0 = fmaf(bf_lo(u0), c0, acc0); acc1 = fmaf(bf_hi(u0), c0, acc1);
        acc0 = fmaf(bf_lo(u1), c1, acc0); acc1 = fmaf(bf_hi(u1), c1, acc1);
        acc0 = fmaf(bf_lo(u2), c2, acc0); acc1 = fmaf(bf_hi(u2), c2, acc1);
        acc0 = fmaf(bf_lo(u3), c3, acc0); acc1 = fmaf(bf_hi(u3), c3, acc1);
    }
    for (; j < hi; j++) {
        int s = csr_src[j];
        float2 e = *(const float2*)&exbuf[(size_t)j * 2];
        uint u = Hb[(size_t)s * 64 + lane];
        float c = (lane < 32) ? e.x : e.y;
        acc0 = fmaf(bf_lo(u), c, acc0);
        acc1 = fmaf(bf_hi(u), c, acc1);
    }
    float v0 = acc0 * inv + b[2 * lane];
    float v1 = acc1 * inv + b[2 * lane + 1];
    v0 = v0 > 0.f ? v0 : 0.f;
    v1 = v1 > 0.f ? v1 : 0.f;
    *(float2*)&outp[(size_t)node * 128 + 2 * lane] = make_float2(v0, v1);
}

// layer 2: H=1, lane owns channel lane, bf16 ushort gather
__global__ void node_agg2_kernel(const int* __restrict__ rowptr, const int* __restrict__ csr_src,
                                 const ushort* __restrict__ Hb,
                                 const float* __restrict__ as, const float* __restrict__ ad,
                                 const float* __restrict__ b, float* __restrict__ outp,
                                 float* __restrict__ exbuf) {
    int wave = threadIdx.x >> 6;
    int lane = threadIdx.x & 63;
    int node = blockIdx.x * 4 + wave;
    if (node >= N_NODES) return;
    const int lo = rowptr[node], hi = rowptr[node + 1];
    const float adN = ad[node];

    float d = 0.f;
    for (int j = lo + lane; j < hi; j += 64) {
        float ex = __expf(lrelu(as[csr_src[j]] + adN));
        exbuf[j] = ex;
        d += ex;
    }
#pragma unroll
    for (int off = 32; off; off >>= 1) d += __shfl_xor(d, off);
    const float inv = 1.f / d;

    float acc = 0.f;
    int j = lo;
    for (; j + 4 <= hi; j += 4) {
        int s0 = csr_src[j + 0], s1 = csr_src[j + 1];
        int s2 = csr_src[j + 2], s3 = csr_src[j + 3];
        float e0 = exbuf[j + 0], e1 = exbuf[j + 1];
        float e2 = exbuf[j + 2], e3 = exbuf[j + 3];
        float h0 = __uint_as_float(((uint)Hb[(size_t)s0 * 64 + lane]) << 16);
        float h1 = __uint_as_float(((uint)Hb[(size_t)s1 * 64 + lane]) << 16);
        float h2 = __uint_as_float(((uint)Hb[(size_t)s2 * 64 + lane]) << 16);
        float h3 = __uint_as_float(((uint)Hb[(size_t)s3 * 64 + lane]) << 16);
        acc = fmaf(h0, e0, acc);
        acc = fmaf(h1, e1, acc);
        acc = fmaf(h2, e2, acc);
        acc = fmaf(h3, e3, acc);
    }
    for (; j < hi; j++)
        acc = fmaf(__uint_as_float(((uint)Hb[(size_t)csr_src[j] * 64 + lane]) << 16),
                   exbuf[j], acc);
    float v = acc * inv + b[lane];
    outp[(size_t)node * 64 + lane] = v > 0.f ? v : 0.f;
}

// ---------- pool + fc + log_softmax: 4 waves per graph ----------
__global__ void pool_fc_kernel(const float* __restrict__ act2,
                               const int* __restrict__ batch,
                               const float* __restrict__ fcW,
                               const float* __restrict__ fcb,
                               float* __restrict__ out) {
    int g = blockIdx.x;
    int tid = threadIdx.x;            // 256
    int wid = tid >> 6, c = tid & 63;
    __shared__ int slo, shi;
    if (tid == 0) {
        int lo = 0, hi = N_NODES;
        while (lo < hi) { int m = (lo + hi) >> 1; if (batch[m] < g) lo = m + 1; else hi = m; }
        slo = lo;
        lo = 0; hi = N_NODES;
        while (lo < hi) { int m = (lo + hi) >> 1; if (batch[m] < g + 1) lo = m + 1; else hi = m; }
        shi = lo;
    }
    __syncthreads();
    const int lo = slo, hi = shi;
    float sum = 0.f;
    for (int n = lo + wid; n < hi; n += 4) sum += act2[(size_t)n * HID + c];
    __shared__ float ps[4][HID];
    ps[wid][c] = sum;
    __syncthreads();
    if (wid == 0) {
        float t = ps[0][c] + ps[1][c] + ps[2][c] + ps[3][c];
        float cnt = (float)(hi - lo);
        __shared__ float pooled[HID];
        pooled[c] = t / fmaxf(cnt, 1.f);
        __syncthreads();
        __shared__ float ls[OUT_DIM];
        if (c < OUT_DIM) {
            float l = fcb[c];
#pragma unroll 8
            for (int k = 0; k < HID; k++) l = fmaf(pooled[k], fcW[k * OUT_DIM + c], l);
            ls[c] = l;
        }
        __syncthreads();
        if (c < OUT_DIM) {
            float m = fmaxf(ls[0], ls[1]);
            float lse = m + logf(expf(ls[0] - m) + expf(ls[1] - m));
            out[(size_t)g * OUT_DIM + c] = ls[c] - lse;
        }
    }
}

extern "C" void kernel_launch(void* const* d_in, const int* in_sizes, int n_in,
                              void* d_out, int out_size, void* d_ws, size_t ws_size,
                              hipStream_t stream) {
    const float* x    = (const float*)d_in[0];
    const int*   ei   = (const int*)d_in[1];
    const int*   batch= (const int*)d_in[2];
    const float* W1   = (const float*)d_in[3];
    const float* as1w = (const float*)d_in[4];
    const float* ad1w = (const float*)d_in[5];
    const float* b1   = (const float*)d_in[6];
    const float* W2   = (const float*)d_in[7];
    const float* as2w = (const float*)d_in[8];
    const float* ad2w = (const float*)d_in[9];
    const float* b2   = (const float*)d_in[10];
    const float* fcW  = (const float*)d_in[11];
    const float* fcb  = (const float*)d_in[12];

    const size_t N = N_NODES;
    float* ws = (float*)d_ws;
    ushort* h1b  = (ushort*)ws;               // N*128 bf16 = N*64 floats
    float* act1  = ws + N * 64;               // N*128 fp32
    ushort* h2b  = (ushort*)(act1 + N * 128); // N*64 bf16 = N*32 floats
    float* out2  = act1 + N * 128 + N * 32;   // N*64 fp32
    float* alps1 = out2 + N * 64;             // N*2
    float* alpd1 = alps1 + N * 2;             // N*2
    float* alps2 = alpd1 + N * 2;             // N
    float* alpd2 = alps2 + N;                 // N
    int* cnt     = (int*)(alpd2 + N);         // N
    int* rowptr  = cnt + N;                   // N+1
    int* cursor  = rowptr + N + 1;            // N
    int* bsum    = cursor + N;                // NB_SCAN
    int* boff    = bsum + NB_SCAN;            // NB_SCAN
    int* csr_src = boff + NB_SCAN;            // EP
    float* exbuf = (float*)(csr_src + EP);    // EP*2

    // ---- CSR build (shared by both layers) ----
    hipMemsetAsync(cnt, 0, N * sizeof(int), stream);
    hist_kernel<<<(EP + 255) / 256, 256, 0, stream>>>(ei, cnt);
    partial_kernel<<<NB_SCAN, 256, 0, stream>>>(cnt, bsum);
    scanb_kernel<<<1, 256, 0, stream>>>(bsum, boff, rowptr);
    scanc_kernel<<<NB_SCAN, 256, 0, stream>>>(cnt, boff, rowptr, cursor);
    scatter_kernel<<<(EP + 255) / 256, 256, 0, stream>>>(ei, cursor, csr_src);

    // ---- layer 1 (H=2) ----
    gemm_nodes<128, 128, 4><<<(N + 3) / 4, 128, 0, stream>>>(x, W1, h1b, (int)N);
    alphas_kernel<2><<<(N + 255) / 256, 256, 0, stream>>>((const uint*)h1b, as1w, ad1w, alps1, alpd1, (int)N);
    node_agg1_kernel<<<(N + 3) / 4, 256, 0, stream>>>(rowptr, csr_src, (const uint*)h1b, alps1, alpd1, b1, act1, exbuf);

    // ---- layer 2 (H=1) ----
    gemm_nodes<128, 64, 8><<<(N + 7) / 8, 64, 0, stream>>>(act1, W2, h2b, (int)N);
    alphas_kernel<1><<<(N + 255) / 256, 256, 0, stream>>>((const uint*)h2b, as2w, ad2w, alps2, alpd2, (int)N);
    node_agg2_kernel<<<(N + 3) / 4, 256, 0, stream>>>(rowptr, csr_src, h2b, alps2, alpd2, b2, out2, exbuf);

    // ---- pool + fc + log_softmax ----
    pool_fc_kernel<<<N_GRAPHS, 256, 0, stream>>>(out2, batch, fcW, fcb, (float*)d_out);
}

// Round 9
// 351.105 us; speedup vs baseline: 7.4380x; 1.0125x over previous
//
#include <hip/hip_runtime.h>
#include <math.h>

#define N_NODES 50000
#define N_EDGES 800000
#define EP (N_EDGES + N_NODES)   // edges + self loops
#define IN_DIM 128
#define HID 64
#define HEADS 2
#define OUT_DIM 2
#define N_GRAPHS 512
#define NEG_SLOPE 0.2f
#define NB_SCAN 196              // ceil(50000/256)

typedef unsigned int uint;
typedef unsigned short ushort;

// round-to-nearest-even f32 -> bf16
__device__ __forceinline__ ushort f2bf(float f) {
    uint u = __float_as_uint(f);
    u += 0x7fffu + ((u >> 16) & 1u);
    return (ushort)(u >> 16);
}
__device__ __forceinline__ float bf_lo(uint u) { return __uint_as_float(u << 16); }
__device__ __forceinline__ float bf_hi(uint u) { return __uint_as_float(u & 0xffff0000u); }

// ---------- CSR build ----------
__global__ void hist_kernel(const int* __restrict__ ei, int* __restrict__ cnt) {
    int i = blockIdx.x * blockDim.x + threadIdx.x;
    if (i >= EP) return;
    int d = (i < N_EDGES) ? ei[N_EDGES + i] : (i - N_EDGES);
    atomicAdd(&cnt[d], 1);
}

__global__ void partial_kernel(const int* __restrict__ cnt, int* __restrict__ bsum) {
    int tid = threadIdx.x;
    int i = blockIdx.x * 256 + tid;
    int lane = tid & 63, wid = tid >> 6;
    int v = (i < N_NODES) ? cnt[i] : 0;
#pragma unroll
    for (int off = 32; off; off >>= 1) v += __shfl_xor(v, off);
    __shared__ int wsum[4];
    if (lane == 0) wsum[wid] = v;
    __syncthreads();
    if (tid == 0) bsum[blockIdx.x] = wsum[0] + wsum[1] + wsum[2] + wsum[3];
}

__global__ void scanb_kernel(const int* __restrict__ bsum, int* __restrict__ boff,
                             int* __restrict__ rowptr) {
    int tid = threadIdx.x;          // 256
    int lane = tid & 63, wid = tid >> 6;
    int v = (tid < NB_SCAN) ? bsum[tid] : 0;
    int incl = v;
#pragma unroll
    for (int off = 1; off < 64; off <<= 1) {
        int t = __shfl_up(incl, off);
        if (lane >= off) incl += t;
    }
    __shared__ int wt[4];
    if (lane == 63) wt[wid] = incl;
    __syncthreads();
    int add = 0;
    for (int w = 0; w < wid; w++) add += wt[w];
    incl += add;
    if (tid < NB_SCAN) boff[tid] = incl - v;
    if (tid == NB_SCAN - 1) rowptr[N_NODES] = incl;
}

__global__ void scanc_kernel(const int* __restrict__ cnt, const int* __restrict__ boff,
                             int* __restrict__ rowptr, int* __restrict__ cursor) {
    int tid = threadIdx.x;
    int i = blockIdx.x * 256 + tid;
    int lane = tid & 63, wid = tid >> 6;
    int v = (i < N_NODES) ? cnt[i] : 0;
    int incl = v;
#pragma unroll
    for (int off = 1; off < 64; off <<= 1) {
        int t = __shfl_up(incl, off);
        if (lane >= off) incl += t;
    }
    __shared__ int wt[4];
    if (lane == 63) wt[wid] = incl;
    __syncthreads();
    int add = boff[blockIdx.x];
    for (int w = 0; w < wid; w++) add += wt[w];
    int excl = add + incl - v;
    if (i < N_NODES) { rowptr[i] = excl; cursor[i] = excl; }
}

__global__ void scatter_kernel(const int* __restrict__ ei, int* __restrict__ cursor,
                               int* __restrict__ csr_src) {
    int i = blockIdx.x * blockDim.x + threadIdx.x;
    if (i >= EP) return;
    int s, d;
    if (i < N_EDGES) { s = ei[i]; d = ei[N_EDGES + i]; }
    else             { s = d = i - N_EDGES; }
    int pos = atomicAdd(&cursor[d], 1);
    csr_src[pos] = s;
}

// ---------- dense GEMM + fused attention-logit reduction ----------
// Y (bf16) = X @ W; as[n][h] = <h[n,h,:], a_src[h,:]>, ad likewise.
// COLS = H*64 threads; thread tid holds channel tid; wave wid = head.
template<int K, int COLS, int NPB, int H>
__global__ void gemm_alphas(const float* __restrict__ X, const float* __restrict__ W,
                            ushort* __restrict__ Y,
                            const float* __restrict__ a_src, const float* __restrict__ a_dst,
                            float* __restrict__ as, float* __restrict__ ad, int n_nodes) {
    __shared__ float xs[NPB][K];
    const int base = blockIdx.x * NPB;
    const int tid = threadIdx.x;
    const int lane = tid & 63, wid = tid >> 6;
    const float4* X4 = (const float4*)X;
    for (int idx = tid; idx < NPB * (K / 4); idx += COLS) {
        int r = idx / (K / 4), c = idx % (K / 4);
        int n = base + r;
        float4 v = (n < n_nodes) ? X4[(size_t)n * (K / 4) + c] : make_float4(0.f, 0.f, 0.f, 0.f);
        ((float4*)xs[r])[c] = v;
    }
    __syncthreads();
    const float asv = a_src[wid * 64 + lane];
    const float adv = a_dst[wid * 64 + lane];
    float acc[NPB];
#pragma unroll
    for (int i = 0; i < NPB; i++) acc[i] = 0.f;
    for (int k = 0; k < K; k++) {
        float w = W[(size_t)k * COLS + tid];
#pragma unroll
        for (int i = 0; i < NPB; i++) acc[i] = fmaf(xs[i][k], w, acc[i]);
    }
#pragma unroll
    for (int i = 0; i < NPB; i++) {
        int n = base + i;
        if (n >= n_nodes) continue;
        Y[(size_t)n * COLS + tid] = f2bf(acc[i]);
        float s = acc[i] * asv;
        float d = acc[i] * adv;
#pragma unroll
        for (int off = 32; off; off >>= 1) {
            s += __shfl_xor(s, off);
            d += __shfl_xor(d, off);
        }
        if (lane == 0) {
            as[(size_t)n * H + wid] = s;
            ad[(size_t)n * H + wid] = d;
        }
    }
}

__device__ __forceinline__ float lrelu(float e) { return e > 0.f ? e : NEG_SLOPE * e; }

// ---------- fused per-node softmax + aggregate + bias + relu ----------
// layer 1: H=2; lane owns channels (2*lane, 2*lane+1) -> head = lane>>5.
// ex values live in registers (edge lo+lane -> exa, lo+64+lane -> exb);
// pass2 broadcasts BOTH heads' values wave-uniformly, then selects per-lane.
__global__ void node_agg1_kernel(const int* __restrict__ rowptr, const int* __restrict__ csr_src,
                                 const uint* __restrict__ Hb,
                                 const float* __restrict__ as, const float* __restrict__ ad,
                                 const float* __restrict__ b, float* __restrict__ outp) {
    int wave = threadIdx.x >> 6;
    int lane = threadIdx.x & 63;
    int node = blockIdx.x * 4 + wave;
    if (node >= N_NODES) return;
    const int lo = rowptr[node], hi = rowptr[node + 1];
    const float ad0 = ad[(size_t)node * 2 + 0], ad1 = ad[(size_t)node * 2 + 1];

    float exa0 = 0.f, exa1 = 0.f, exb0 = 0.f, exb1 = 0.f;
    int j1 = lo + lane;
    if (j1 < hi) {
        int s = csr_src[j1];
        float2 a = *(const float2*)&as[(size_t)s * 2];
        exa0 = __expf(lrelu(a.x + ad0));
        exa1 = __expf(lrelu(a.y + ad1));
    }
    int j2 = lo + 64 + lane;
    if (j2 < hi) {
        int s = csr_src[j2];
        float2 a = *(const float2*)&as[(size_t)s * 2];
        exb0 = __expf(lrelu(a.x + ad0));
        exb1 = __expf(lrelu(a.y + ad1));
    }
    float d0 = exa0 + exb0, d1 = exa1 + exb1;
    for (int j = lo + 128 + lane; j < hi; j += 64) {   // degree > 128 (rare)
        int s = csr_src[j];
        float2 a = *(const float2*)&as[(size_t)s * 2];
        d0 += __expf(lrelu(a.x + ad0));
        d1 += __expf(lrelu(a.y + ad1));
    }
#pragma unroll
    for (int off = 32; off; off >>= 1) {
        d0 += __shfl_xor(d0, off);
        d1 += __shfl_xor(d1, off);
    }
    const float inv = (lane < 32) ? (1.f / d0) : (1.f / d1);
    const bool h0side = (lane < 32);

    float acc0 = 0.f, acc1 = 0.f;
    const int deg = hi - lo;
    const int n1 = deg < 64 ? deg : 64;
    int j = 0;
    for (; j + 4 <= n1; j += 4) {
        int s0 = csr_src[lo + j + 0], s1 = csr_src[lo + j + 1];
        int s2 = csr_src[lo + j + 2], s3 = csr_src[lo + j + 3];
        // wave-uniform shuffles (ALL lanes participate), then per-lane select
        float ca0 = __shfl(exa0, j + 0), cb0 = __shfl(exa1, j + 0);
        float ca1 = __shfl(exa0, j + 1), cb1 = __shfl(exa1, j + 1);
        float ca2 = __shfl(exa0, j + 2), cb2 = __shfl(exa1, j + 2);
        float ca3 = __shfl(exa0, j + 3), cb3 = __shfl(exa1, j + 3);
        float c0 = h0side ? ca0 : cb0;
        float c1 = h0side ? ca1 : cb1;
        float c2 = h0side ? ca2 : cb2;
        float c3 = h0side ? ca3 : cb3;
        uint u0 = Hb[(size_t)s0 * 64 + lane];
        uint u1 = Hb[(size_t)s1 * 64 + lane];
        uint u2 = Hb[(size_t)s2 * 64 + lane];
        uint u3 = Hb[(size_t)s3 * 64 + lane];
        acc0 = fmaf(bf_lo(u0), c0, acc0); acc1 = fmaf(bf_hi(u0), c0, acc1);
        acc0 = fmaf(bf_lo(u1), c1, acc0); acc1 = fmaf(bf_hi(u1), c1, acc1);
        acc0 = fmaf(bf_lo(u2), c2, acc0); acc1 = fmaf(bf_hi(u2), c2, acc1);
        acc0 = fmaf(bf_lo(u3), c3, acc0); acc1 = fmaf(bf_hi(u3), c3, acc1);
    }
    for (; j < n1; j++) {
        int s = csr_src[lo + j];
        float ca = __shfl(exa0, j), cb = __shfl(exa1, j);
        float c = h0side ? ca : cb;
        uint u = Hb[(size_t)s * 64 + lane];
        acc0 = fmaf(bf_lo(u), c, acc0);
        acc1 = fmaf(bf_hi(u), c, acc1);
    }
    if (deg > 64) {
        const int n2 = deg < 128 ? deg : 128;
        for (j = 64; j < n2; j++) {
            int s = csr_src[lo + j];
            float ca = __shfl(exb0, j - 64), cb = __shfl(exb1, j - 64);
            float c = h0side ? ca : cb;
            uint u = Hb[(size_t)s * 64 + lane];
            acc0 = fmaf(bf_lo(u), c, acc0);
            acc1 = fmaf(bf_hi(u), c, acc1);
        }
        for (int jj = lo + 128; jj < hi; jj++) {       // rare; lane-local, no shfl
            int s = csr_src[jj];
            float2 a = *(const float2*)&as[(size_t)s * 2];
            float e0 = __expf(lrelu(a.x + ad0));
            float e1 = __expf(lrelu(a.y + ad1));
            float c = h0side ? e0 : e1;
            uint u = Hb[(size_t)s * 64 + lane];
            acc0 = fmaf(bf_lo(u), c, acc0);
            acc1 = fmaf(bf_hi(u), c, acc1);
        }
    }
    float v0 = acc0 * inv + b[2 * lane];
    float v1 = acc1 * inv + b[2 * lane + 1];
    v0 = v0 > 0.f ? v0 : 0.f;
    v1 = v1 > 0.f ? v1 : 0.f;
    *(float2*)&outp[(size_t)node * 128 + 2 * lane] = make_float2(v0, v1);
}

// layer 2: H=1, lane owns channel lane, bf16 ushort gather (shuffles already uniform)
__global__ void node_agg2_kernel(const int* __restrict__ rowptr, const int* __restrict__ csr_src,
                                 const ushort* __restrict__ Hb,
                                 const float* __restrict__ as, const float* __restrict__ ad,
                                 const float* __restrict__ b, float* __restrict__ outp) {
    int wave = threadIdx.x >> 6;
    int lane = threadIdx.x & 63;
    int node = blockIdx.x * 4 + wave;
    if (node >= N_NODES) return;
    const int lo = rowptr[node], hi = rowptr[node + 1];
    const float adN = ad[node];

    float exa = 0.f, exb = 0.f;
    int j1 = lo + lane;
    if (j1 < hi) exa = __expf(lrelu(as[csr_src[j1]] + adN));
    int j2 = lo + 64 + lane;
    if (j2 < hi) exb = __expf(lrelu(as[csr_src[j2]] + adN));
    float d = exa + exb;
    for (int j = lo + 128 + lane; j < hi; j += 64)
        d += __expf(lrelu(as[csr_src[j]] + adN));
#pragma unroll
    for (int off = 32; off; off >>= 1) d += __shfl_xor(d, off);
    const float inv = 1.f / d;

    float acc = 0.f;
    const int deg = hi - lo;
    const int n1 = deg < 64 ? deg : 64;
    int j = 0;
    for (; j + 4 <= n1; j += 4) {
        int s0 = csr_src[lo + j + 0], s1 = csr_src[lo + j + 1];
        int s2 = csr_src[lo + j + 2], s3 = csr_src[lo + j + 3];
        float c0 = __shfl(exa, j + 0), c1 = __shfl(exa, j + 1);
        float c2 = __shfl(exa, j + 2), c3 = __shfl(exa, j + 3);
        float h0 = __uint_as_float(((uint)Hb[(size_t)s0 * 64 + lane]) << 16);
        float h1 = __uint_as_float(((uint)Hb[(size_t)s1 * 64 + lane]) << 16);
        float h2 = __uint_as_float(((uint)Hb[(size_t)s2 * 64 + lane]) << 16);
        float h3 = __uint_as_float(((uint)Hb[(size_t)s3 * 64 + lane]) << 16);
        acc = fmaf(h0, c0, acc);
        acc = fmaf(h1, c1, acc);
        acc = fmaf(h2, c2, acc);
        acc = fmaf(h3, c3, acc);
    }
    for (; j < n1; j++) {
        float c = __shfl(exa, j);
        acc = fmaf(__uint_as_float(((uint)Hb[(size_t)csr_src[lo + j] * 64 + lane]) << 16), c, acc);
    }
    if (deg > 64) {
        const int n2 = deg < 128 ? deg : 128;
        for (j = 64; j < n2; j++) {
            float c = __shfl(exb, j - 64);
            acc = fmaf(__uint_as_float(((uint)Hb[(size_t)csr_src[lo + j] * 64 + lane]) << 16), c, acc);
        }
        for (int jj = lo + 128; jj < hi; jj++) {       // rare
            int s = csr_src[jj];
            float c = __expf(lrelu(as[s] + adN));
            acc = fmaf(__uint_as_float(((uint)Hb[(size_t)s * 64 + lane]) << 16), c, acc);
        }
    }
    float v = acc * inv + b[lane];
    outp[(size_t)node * 64 + lane] = v > 0.f ? v : 0.f;
}

// ---------- pool + fc + log_softmax: 4 waves per graph ----------
__global__ void pool_fc_kernel(const float* __restrict__ act2,
                               const int* __restrict__ batch,
                               const float* __restrict__ fcW,
                               const float* __restrict__ fcb,
                               float* __restrict__ out) {
    int g = blockIdx.x;
    int tid = threadIdx.x;            // 256
    int wid = tid >> 6, c = tid & 63;
    __shared__ int slo, shi;
    if (tid == 0) {
        int lo = 0, hi = N_NODES;
        while (lo < hi) { int m = (lo + hi) >> 1; if (batch[m] < g) lo = m + 1; else hi = m; }
        slo = lo;
        lo = 0; hi = N_NODES;
        while (lo < hi) { int m = (lo + hi) >> 1; if (batch[m] < g + 1) lo = m + 1; else hi = m; }
        shi = lo;
    }
    __syncthreads();
    const int lo = slo, hi = shi;
    float sum = 0.f;
    for (int n = lo + wid; n < hi; n += 4) sum += act2[(size_t)n * HID + c];
    __shared__ float ps[4][HID];
    ps[wid][c] = sum;
    __syncthreads();
    if (wid == 0) {
        float t = ps[0][c] + ps[1][c] + ps[2][c] + ps[3][c];
        float cnt = (float)(hi - lo);
        __shared__ float pooled[HID];
        pooled[c] = t / fmaxf(cnt, 1.f);
        __syncthreads();
        __shared__ float ls[OUT_DIM];
        if (c < OUT_DIM) {
            float l = fcb[c];
#pragma unroll 8
            for (int k = 0; k < HID; k++) l = fmaf(pooled[k], fcW[k * OUT_DIM + c], l);
            ls[c] = l;
        }
        __syncthreads();
        if (c < OUT_DIM) {
            float m = fmaxf(ls[0], ls[1]);
            float lse = m + logf(expf(ls[0] - m) + expf(ls[1] - m));
            out[(size_t)g * OUT_DIM + c] = ls[c] - lse;
        }
    }
}

extern "C" void kernel_launch(void* const* d_in, const int* in_sizes, int n_in,
                              void* d_out, int out_size, void* d_ws, size_t ws_size,
                              hipStream_t stream) {
    const float* x    = (const float*)d_in[0];
    const int*   ei   = (const int*)d_in[1];
    const int*   batch= (const int*)d_in[2];
    const float* W1   = (const float*)d_in[3];
    const float* as1w = (const float*)d_in[4];
    const float* ad1w = (const float*)d_in[5];
    const float* b1   = (const float*)d_in[6];
    const float* W2   = (const float*)d_in[7];
    const float* as2w = (const float*)d_in[8];
    const float* ad2w = (const float*)d_in[9];
    const float* b2   = (const float*)d_in[10];
    const float* fcW  = (const float*)d_in[11];
    const float* fcb  = (const float*)d_in[12];

    const size_t N = N_NODES;
    float* ws = (float*)d_ws;
    ushort* h1b  = (ushort*)ws;               // N*128 bf16 = N*64 floats
    float* act1  = ws + N * 64;               // N*128 fp32
    ushort* h2b  = (ushort*)(act1 + N * 128); // N*64 bf16 = N*32 floats
    float* out2  = act1 + N * 128 + N * 32;   // N*64 fp32
    float* alps1 = out2 + N * 64;             // N*2
    float* alpd1 = alps1 + N * 2;             // N*2
    float* alps2 = alpd1 + N * 2;             // N
    float* alpd2 = alps2 + N;                 // N
    int* cnt     = (int*)(alpd2 + N);         // N
    int* rowptr  = cnt + N;                   // N+1
    int* cursor  = rowptr + N + 1;            // N
    int* bsum    = cursor + N;                // NB_SCAN
    int* boff    = bsum + NB_SCAN;            // NB_SCAN
    int* csr_src = boff + NB_SCAN;            // EP

    // ---- CSR build (shared by both layers) ----
    hipMemsetAsync(cnt, 0, N * sizeof(int), stream);
    hist_kernel<<<(EP + 255) / 256, 256, 0, stream>>>(ei, cnt);
    partial_kernel<<<NB_SCAN, 256, 0, stream>>>(cnt, bsum);
    scanb_kernel<<<1, 256, 0, stream>>>(bsum, boff, rowptr);
    scanc_kernel<<<NB_SCAN, 256, 0, stream>>>(cnt, boff, rowptr, cursor);
    scatter_kernel<<<(EP + 255) / 256, 256, 0, stream>>>(ei, cursor, csr_src);

    // ---- layer 1 (H=2) ----
    gemm_alphas<128, 128, 4, 2><<<(N + 3) / 4, 128, 0, stream>>>(
        x, W1, h1b, as1w, ad1w, alps1, alpd1, (int)N);
    node_agg1_kernel<<<(N + 3) / 4, 256, 0, stream>>>(
        rowptr, csr_src, (const uint*)h1b, alps1, alpd1, b1, act1);

    // ---- layer 2 (H=1) ----
    gemm_alphas<128, 64, 8, 1><<<(N + 7) / 8, 64, 0, stream>>>(
        act1, W2, h2b, as2w, ad2w, alps2, alpd2, (int)N);
    node_agg2_kernel<<<(N + 3) / 4, 256, 0, stream>>>(
        rowptr, csr_src, h2b, alps2, alpd2, b2, out2);

    // ---- pool + fc + log_softmax ----
    pool_fc_kernel<<<N_GRAPHS, 256, 0, stream>>>(out2, batch, fcW, fcb, (float*)d_out);
}

// Round 10
// 310.499 us; speedup vs baseline: 8.4108x; 1.1308x over previous
//
#include <hip/hip_runtime.h>
#include <math.h>

#define N_NODES 50000
#define N_EDGES 800000
#define EP (N_EDGES + N_NODES)   // edges + self loops
#define IN_DIM 128
#define HID 64
#define HEADS 2
#define OUT_DIM 2
#define N_GRAPHS 512
#define NEG_SLOPE 0.2f
#define NB_SCAN 196              // ceil(50000/256)

typedef unsigned int uint;
typedef unsigned short ushort;

// round-to-nearest-even f32 -> bf16
__device__ __forceinline__ ushort f2bf(float f) {
    uint u = __float_as_uint(f);
    u += 0x7fffu + ((u >> 16) & 1u);
    return (ushort)(u >> 16);
}
__device__ __forceinline__ float bf_lo(uint u) { return __uint_as_float(u << 16); }
__device__ __forceinline__ float bf_hi(uint u) { return __uint_as_float(u & 0xffff0000u); }

// ---------- CSR build ----------
// hist: atomicAdd returns each edge's rank within its destination segment.
__global__ void hist_kernel(const int* __restrict__ ei, int* __restrict__ cnt,
                            int* __restrict__ erank) {
    int i = blockIdx.x * blockDim.x + threadIdx.x;
    if (i >= EP) return;
    int d = (i < N_EDGES) ? ei[N_EDGES + i] : (i - N_EDGES);
    erank[i] = atomicAdd(&cnt[d], 1);
}

__global__ void partial_kernel(const int* __restrict__ cnt, int* __restrict__ bsum) {
    int tid = threadIdx.x;
    int i = blockIdx.x * 256 + tid;
    int lane = tid & 63, wid = tid >> 6;
    int v = (i < N_NODES) ? cnt[i] : 0;
#pragma unroll
    for (int off = 32; off; off >>= 1) v += __shfl_xor(v, off);
    __shared__ int wsum[4];
    if (lane == 0) wsum[wid] = v;
    __syncthreads();
    if (tid == 0) bsum[blockIdx.x] = wsum[0] + wsum[1] + wsum[2] + wsum[3];
}

__global__ void scanb_kernel(const int* __restrict__ bsum, int* __restrict__ boff,
                             int* __restrict__ rowptr) {
    int tid = threadIdx.x;          // 256
    int lane = tid & 63, wid = tid >> 6;
    int v = (tid < NB_SCAN) ? bsum[tid] : 0;
    int incl = v;
#pragma unroll
    for (int off = 1; off < 64; off <<= 1) {
        int t = __shfl_up(incl, off);
        if (lane >= off) incl += t;
    }
    __shared__ int wt[4];
    if (lane == 63) wt[wid] = incl;
    __syncthreads();
    int add = 0;
    for (int w = 0; w < wid; w++) add += wt[w];
    incl += add;
    if (tid < NB_SCAN) boff[tid] = incl - v;
    if (tid == NB_SCAN - 1) rowptr[N_NODES] = incl;
}

__global__ void scanc_kernel(const int* __restrict__ cnt, const int* __restrict__ boff,
                             int* __restrict__ rowptr) {
    int tid = threadIdx.x;
    int i = blockIdx.x * 256 + tid;
    int lane = tid & 63, wid = tid >> 6;
    int v = (i < N_NODES) ? cnt[i] : 0;
    int incl = v;
#pragma unroll
    for (int off = 1; off < 64; off <<= 1) {
        int t = __shfl_up(incl, off);
        if (lane >= off) incl += t;
    }
    __shared__ int wt[4];
    if (lane == 63) wt[wid] = incl;
    __syncthreads();
    int add = boff[blockIdx.x];
    for (int w = 0; w < wid; w++) add += wt[w];
    int excl = add + incl - v;
    if (i < N_NODES) rowptr[i] = excl;
}

// scatter with NO atomics: pos = rowptr[d] + erank[i]
__global__ void scatter_kernel(const int* __restrict__ ei, const int* __restrict__ rowptr,
                               const int* __restrict__ erank, int* __restrict__ csr_src) {
    int i = blockIdx.x * blockDim.x + threadIdx.x;
    if (i >= EP) return;
    int s, d;
    if (i < N_EDGES) { s = ei[i]; d = ei[N_EDGES + i]; }
    else             { s = d = i - N_EDGES; }
    csr_src[rowptr[d] + erank[i]] = s;
}

// ---------- layer-1 GEMM + fused alphas ----------
// 1 wave (64 threads) per block, 8 nodes per block, 128 cols.
// Thread t owns cols t (head 0) and 64+t (head 1); 2-col x 8-row register tile.
__global__ void gemm_alphas1(const float* __restrict__ X, const float* __restrict__ W,
                             ushort* __restrict__ Y,
                             const float* __restrict__ a_src, const float* __restrict__ a_dst,
                             float* __restrict__ as, float* __restrict__ ad, int n_nodes) {
    __shared__ float xs[8][128];
    const int base = blockIdx.x * 8;
    const int t = threadIdx.x;                 // 0..63
    const float4* X4 = (const float4*)X;
    for (int idx = t; idx < 8 * 32; idx += 64) {
        int r = idx >> 5, c = idx & 31;
        int n = base + r;
        float4 v = (n < n_nodes) ? X4[(size_t)n * 32 + c] : make_float4(0.f, 0.f, 0.f, 0.f);
        ((float4*)xs[r])[c] = v;
    }
    __syncthreads();

    float acc0[8], acc1[8];
#pragma unroll
    for (int i = 0; i < 8; i++) { acc0[i] = 0.f; acc1[i] = 0.f; }
    for (int k = 0; k < 128; k += 4) {
        float wA[4], wB[4];
#pragma unroll
        for (int kk = 0; kk < 4; kk++) {
            wA[kk] = W[(size_t)(k + kk) * 128 + t];
            wB[kk] = W[(size_t)(k + kk) * 128 + 64 + t];
        }
#pragma unroll
        for (int i = 0; i < 8; i++) {
            float4 xv = *(const float4*)&xs[i][k];
            float xx0 = xv.x, xx1 = xv.y, xx2 = xv.z, xx3 = xv.w;
            acc0[i] = fmaf(xx0, wA[0], acc0[i]); acc1[i] = fmaf(xx0, wB[0], acc1[i]);
            acc0[i] = fmaf(xx1, wA[1], acc0[i]); acc1[i] = fmaf(xx1, wB[1], acc1[i]);
            acc0[i] = fmaf(xx2, wA[2], acc0[i]); acc1[i] = fmaf(xx2, wB[2], acc1[i]);
            acc0[i] = fmaf(xx3, wA[3], acc0[i]); acc1[i] = fmaf(xx3, wB[3], acc1[i]);
        }
    }

    const float asv0 = a_src[t],      adv0 = a_dst[t];
    const float asv1 = a_src[64 + t], adv1 = a_dst[64 + t];
#pragma unroll
    for (int i = 0; i < 8; i++) {
        int n = base + i;
        if (n >= n_nodes) continue;
        Y[(size_t)n * 128 + t]      = f2bf(acc0[i]);
        Y[(size_t)n * 128 + 64 + t] = f2bf(acc1[i]);
        float s0 = acc0[i] * asv0, d0 = acc0[i] * adv0;
        float s1 = acc1[i] * asv1, d1 = acc1[i] * adv1;
#pragma unroll
        for (int off = 32; off; off >>= 1) {
            s0 += __shfl_xor(s0, off);
            d0 += __shfl_xor(d0, off);
            s1 += __shfl_xor(s1, off);
            d1 += __shfl_xor(d1, off);
        }
        if (t == 0) {
            as[(size_t)n * 2 + 0] = s0; as[(size_t)n * 2 + 1] = s1;
            ad[(size_t)n * 2 + 0] = d0; ad[(size_t)n * 2 + 1] = d1;
        }
    }
}

// ---------- layer-2 GEMM + fused alphas ----------
// 1 wave per block, 8 nodes, 64 cols. Thread t: row-group g=t>>5 (rows 4g..4g+3),
// cols c=t&31 and c+32. Alpha reduce within each 32-lane half.
__global__ void gemm_alphas2(const float* __restrict__ X, const float* __restrict__ W,
                             ushort* __restrict__ Y,
                             const float* __restrict__ a_src, const float* __restrict__ a_dst,
                             float* __restrict__ as, float* __restrict__ ad, int n_nodes) {
    __shared__ float xs[8][128];
    const int base = blockIdx.x * 8;
    const int t = threadIdx.x;                 // 0..63
    const int g = t >> 5, c = t & 31;
    const float4* X4 = (const float4*)X;
    for (int idx = t; idx < 8 * 32; idx += 64) {
        int r = idx >> 5, cc = idx & 31;
        int n = base + r;
        float4 v = (n < n_nodes) ? X4[(size_t)n * 32 + cc] : make_float4(0.f, 0.f, 0.f, 0.f);
        ((float4*)xs[r])[cc] = v;
    }
    __syncthreads();

    float acc0[4], acc1[4];
#pragma unroll
    for (int i = 0; i < 4; i++) { acc0[i] = 0.f; acc1[i] = 0.f; }
    for (int k = 0; k < 128; k += 4) {
        float wA[4], wB[4];
#pragma unroll
        for (int kk = 0; kk < 4; kk++) {
            wA[kk] = W[(size_t)(k + kk) * 64 + c];
            wB[kk] = W[(size_t)(k + kk) * 64 + 32 + c];
        }
#pragma unroll
        for (int i = 0; i < 4; i++) {
            float4 xv = *(const float4*)&xs[g * 4 + i][k];
            float xx0 = xv.x, xx1 = xv.y, xx2 = xv.z, xx3 = xv.w;
            acc0[i] = fmaf(xx0, wA[0], acc0[i]); acc1[i] = fmaf(xx0, wB[0], acc1[i]);
            acc0[i] = fmaf(xx1, wA[1], acc0[i]); acc1[i] = fmaf(xx1, wB[1], acc1[i]);
            acc0[i] = fmaf(xx2, wA[2], acc0[i]); acc1[i] = fmaf(xx2, wB[2], acc1[i]);
            acc0[i] = fmaf(xx3, wA[3], acc0[i]); acc1[i] = fmaf(xx3, wB[3], acc1[i]);
        }
    }

    const float asvA = a_src[c], asvB = a_src[32 + c];
    const float advA = a_dst[c], advB = a_dst[32 + c];
#pragma unroll
    for (int i = 0; i < 4; i++) {
        int n = base + g * 4 + i;
        if (n >= n_nodes) continue;
        Y[(size_t)n * 64 + c]      = f2bf(acc0[i]);
        Y[(size_t)n * 64 + 32 + c] = f2bf(acc1[i]);
        float s = acc0[i] * asvA + acc1[i] * asvB;
        float d = acc0[i] * advA + acc1[i] * advB;
#pragma unroll
        for (int off = 16; off; off >>= 1) {
            s += __shfl_xor(s, off);
            d += __shfl_xor(d, off);
        }
        if (c == 0) { as[n] = s; ad[n] = d; }
    }
}

__device__ __forceinline__ float lrelu(float e) { return e > 0.f ? e : NEG_SLOPE * e; }

// ---------- fused per-node softmax + aggregate + bias + relu ----------
__global__ void node_agg1_kernel(const int* __restrict__ rowptr, const int* __restrict__ csr_src,
                                 const uint* __restrict__ Hb,
                                 const float* __restrict__ as, const float* __restrict__ ad,
                                 const float* __restrict__ b, float* __restrict__ outp) {
    int wave = threadIdx.x >> 6;
    int lane = threadIdx.x & 63;
    int node = blockIdx.x * 4 + wave;
    if (node >= N_NODES) return;
    const int lo = rowptr[node], hi = rowptr[node + 1];
    const float ad0 = ad[(size_t)node * 2 + 0], ad1 = ad[(size_t)node * 2 + 1];

    float exa0 = 0.f, exa1 = 0.f, exb0 = 0.f, exb1 = 0.f;
    int j1 = lo + lane;
    if (j1 < hi) {
        int s = csr_src[j1];
        float2 a = *(const float2*)&as[(size_t)s * 2];
        exa0 = __expf(lrelu(a.x + ad0));
        exa1 = __expf(lrelu(a.y + ad1));
    }
    int j2 = lo + 64 + lane;
    if (j2 < hi) {
        int s = csr_src[j2];
        float2 a = *(const float2*)&as[(size_t)s * 2];
        exb0 = __expf(lrelu(a.x + ad0));
        exb1 = __expf(lrelu(a.y + ad1));
    }
    float d0 = exa0 + exb0, d1 = exa1 + exb1;
    for (int j = lo + 128 + lane; j < hi; j += 64) {   // degree > 128 (rare)
        int s = csr_src[j];
        float2 a = *(const float2*)&as[(size_t)s * 2];
        d0 += __expf(lrelu(a.x + ad0));
        d1 += __expf(lrelu(a.y + ad1));
    }
#pragma unroll
    for (int off = 32; off; off >>= 1) {
        d0 += __shfl_xor(d0, off);
        d1 += __shfl_xor(d1, off);
    }
    const float inv = (lane < 32) ? (1.f / d0) : (1.f / d1);
    const bool h0side = (lane < 32);

    float acc0 = 0.f, acc1 = 0.f;
    const int deg = hi - lo;
    const int n1 = deg < 64 ? deg : 64;
    int j = 0;
    for (; j + 4 <= n1; j += 4) {
        int s0 = csr_src[lo + j + 0], s1 = csr_src[lo + j + 1];
        int s2 = csr_src[lo + j + 2], s3 = csr_src[lo + j + 3];
        float ca0 = __shfl(exa0, j + 0), cb0 = __shfl(exa1, j + 0);
        float ca1 = __shfl(exa0, j + 1), cb1 = __shfl(exa1, j + 1);
        float ca2 = __shfl(exa0, j + 2), cb2 = __shfl(exa1, j + 2);
        float ca3 = __shfl(exa0, j + 3), cb3 = __shfl(exa1, j + 3);
        float c0 = h0side ? ca0 : cb0;
        float c1 = h0side ? ca1 : cb1;
        float c2 = h0side ? ca2 : cb2;
        float c3 = h0side ? ca3 : cb3;
        uint u0 = Hb[(size_t)s0 * 64 + lane];
        uint u1 = Hb[(size_t)s1 * 64 + lane];
        uint u2 = Hb[(size_t)s2 * 64 + lane];
        uint u3 = Hb[(size_t)s3 * 64 + lane];
        acc0 = fmaf(bf_lo(u0), c0, acc0); acc1 = fmaf(bf_hi(u0), c0, acc1);
        acc0 = fmaf(bf_lo(u1), c1, acc0); acc1 = fmaf(bf_hi(u1), c1, acc1);
        acc0 = fmaf(bf_lo(u2), c2, acc0); acc1 = fmaf(bf_hi(u2), c2, acc1);
        acc0 = fmaf(bf_lo(u3), c3, acc0); acc1 = fmaf(bf_hi(u3), c3, acc1);
    }
    for (; j < n1; j++) {
        int s = csr_src[lo + j];
        float ca = __shfl(exa0, j), cb = __shfl(exa1, j);
        float c = h0side ? ca : cb;
        uint u = Hb[(size_t)s * 64 + lane];
        acc0 = fmaf(bf_lo(u), c, acc0);
        acc1 = fmaf(bf_hi(u), c, acc1);
    }
    if (deg > 64) {
        const int n2 = deg < 128 ? deg : 128;
        for (j = 64; j < n2; j++) {
            int s = csr_src[lo + j];
            float ca = __shfl(exb0, j - 64), cb = __shfl(exb1, j - 64);
            float c = h0side ? ca : cb;
            uint u = Hb[(size_t)s * 64 + lane];
            acc0 = fmaf(bf_lo(u), c, acc0);
            acc1 = fmaf(bf_hi(u), c, acc1);
        }
        for (int jj = lo + 128; jj < hi; jj++) {       // rare; lane-local, no shfl
            int s = csr_src[jj];
            float2 a = *(const float2*)&as[(size_t)s * 2];
            float e0 = __expf(lrelu(a.x + ad0));
            float e1 = __expf(lrelu(a.y + ad1));
            float c = h0side ? e0 : e1;
            uint u = Hb[(size_t)s * 64 + lane];
            acc0 = fmaf(bf_lo(u), c, acc0);
            acc1 = fmaf(bf_hi(u), c, acc1);
        }
    }
    float v0 = acc0 * inv + b[2 * lane];
    float v1 = acc1 * inv + b[2 * lane + 1];
    v0 = v0 > 0.f ? v0 : 0.f;
    v1 = v1 > 0.f ? v1 : 0.f;
    *(float2*)&outp[(size_t)node * 128 + 2 * lane] = make_float2(v0, v1);
}

__global__ void node_agg2_kernel(const int* __restrict__ rowptr, const int* __restrict__ csr_src,
                                 const ushort* __restrict__ Hb,
                                 const float* __restrict__ as, const float* __restrict__ ad,
                                 const float* __restrict__ b, float* __restrict__ outp) {
    int wave = threadIdx.x >> 6;
    int lane = threadIdx.x & 63;
    int node = blockIdx.x * 4 + wave;
    if (node >= N_NODES) return;
    const int lo = rowptr[node], hi = rowptr[node + 1];
    const float adN = ad[node];

    float exa = 0.f, exb = 0.f;
    int j1 = lo + lane;
    if (j1 < hi) exa = __expf(lrelu(as[csr_src[j1]] + adN));
    int j2 = lo + 64 + lane;
    if (j2 < hi) exb = __expf(lrelu(as[csr_src[j2]] + adN));
    float d = exa + exb;
    for (int j = lo + 128 + lane; j < hi; j += 64)
        d += __expf(lrelu(as[csr_src[j]] + adN));
#pragma unroll
    for (int off = 32; off; off >>= 1) d += __shfl_xor(d, off);
    const float inv = 1.f / d;

    float acc = 0.f;
    const int deg = hi - lo;
    const int n1 = deg < 64 ? deg : 64;
    int j = 0;
    for (; j + 4 <= n1; j += 4) {
        int s0 = csr_src[lo + j + 0], s1 = csr_src[lo + j + 1];
        int s2 = csr_src[lo + j + 2], s3 = csr_src[lo + j + 3];
        float c0 = __shfl(exa, j + 0), c1 = __shfl(exa, j + 1);
        float c2 = __shfl(exa, j + 2), c3 = __shfl(exa, j + 3);
        float h0 = __uint_as_float(((uint)Hb[(size_t)s0 * 64 + lane]) << 16);
        float h1 = __uint_as_float(((uint)Hb[(size_t)s1 * 64 + lane]) << 16);
        float h2 = __uint_as_float(((uint)Hb[(size_t)s2 * 64 + lane]) << 16);
        float h3 = __uint_as_float(((uint)Hb[(size_t)s3 * 64 + lane]) << 16);
        acc = fmaf(h0, c0, acc);
        acc = fmaf(h1, c1, acc);
        acc = fmaf(h2, c2, acc);
        acc = fmaf(h3, c3, acc);
    }
    for (; j < n1; j++) {
        float c = __shfl(exa, j);
        acc = fmaf(__uint_as_float(((uint)Hb[(size_t)csr_src[lo + j] * 64 + lane]) << 16), c, acc);
    }
    if (deg > 64) {
        const int n2 = deg < 128 ? deg : 128;
        for (j = 64; j < n2; j++) {
            float c = __shfl(exb, j - 64);
            acc = fmaf(__uint_as_float(((uint)Hb[(size_t)csr_src[lo + j] * 64 + lane]) << 16), c, acc);
        }
        for (int jj = lo + 128; jj < hi; jj++) {       // rare
            int s = csr_src[jj];
            float c = __expf(lrelu(as[s] + adN));
            acc = fmaf(__uint_as_float(((uint)Hb[(size_t)s * 64 + lane]) << 16), c, acc);
        }
    }
    float v = acc * inv + b[lane];
    outp[(size_t)node * 64 + lane] = v > 0.f ? v : 0.f;
}

// ---------- pool + fc + log_softmax: 4 waves per graph ----------
__global__ void pool_fc_kernel(const float* __restrict__ act2,
                               const int* __restrict__ batch,
                               const float* __restrict__ fcW,
                               const float* __restrict__ fcb,
                               float* __restrict__ out) {
    int g = blockIdx.x;
    int tid = threadIdx.x;            // 256
    int wid = tid >> 6, c = tid & 63;
    __shared__ int slo, shi;
    if (tid == 0) {
        int lo = 0, hi = N_NODES;
        while (lo < hi) { int m = (lo + hi) >> 1; if (batch[m] < g) lo = m + 1; else hi = m; }
        slo = lo;
        lo = 0; hi = N_NODES;
        while (lo < hi) { int m = (lo + hi) >> 1; if (batch[m] < g + 1) lo = m + 1; else hi = m; }
        shi = lo;
    }
    __syncthreads();
    const int lo = slo, hi = shi;
    float sum = 0.f;
    for (int n = lo + wid; n < hi; n += 4) sum += act2[(size_t)n * HID + c];
    __shared__ float ps[4][HID];
    ps[wid][c] = sum;
    __syncthreads();
    if (wid == 0) {
        float t = ps[0][c] + ps[1][c] + ps[2][c] + ps[3][c];
        float cnt = (float)(hi - lo);
        __shared__ float pooled[HID];
        pooled[c] = t / fmaxf(cnt, 1.f);
        __syncthreads();
        __shared__ float ls[OUT_DIM];
        if (c < OUT_DIM) {
            float l = fcb[c];
#pragma unroll 8
            for (int k = 0; k < HID; k++) l = fmaf(pooled[k], fcW[k * OUT_DIM + c], l);
            ls[c] = l;
        }
        __syncthreads();
        if (c < OUT_DIM) {
            float m = fmaxf(ls[0], ls[1]);
            float lse = m + logf(expf(ls[0] - m) + expf(ls[1] - m));
            out[(size_t)g * OUT_DIM + c] = ls[c] - lse;
        }
    }
}

extern "C" void kernel_launch(void* const* d_in, const int* in_sizes, int n_in,
                              void* d_out, int out_size, void* d_ws, size_t ws_size,
                              hipStream_t stream) {
    const float* x    = (const float*)d_in[0];
    const int*   ei   = (const int*)d_in[1];
    const int*   batch= (const int*)d_in[2];
    const float* W1   = (const float*)d_in[3];
    const float* as1w = (const float*)d_in[4];
    const float* ad1w = (const float*)d_in[5];
    const float* b1   = (const float*)d_in[6];
    const float* W2   = (const float*)d_in[7];
    const float* as2w = (const float*)d_in[8];
    const float* ad2w = (const float*)d_in[9];
    const float* b2   = (const float*)d_in[10];
    const float* fcW  = (const float*)d_in[11];
    const float* fcb  = (const float*)d_in[12];

    const size_t N = N_NODES;
    float* ws = (float*)d_ws;
    ushort* h1b  = (ushort*)ws;               // N*128 bf16 = N*64 floats
    float* act1  = ws + N * 64;               // N*128 fp32
    ushort* h2b  = (ushort*)(act1 + N * 128); // N*64 bf16 = N*32 floats
    float* out2  = act1 + N * 128 + N * 32;   // N*64 fp32
    float* alps1 = out2 + N * 64;             // N*2
    float* alpd1 = alps1 + N * 2;             // N*2
    float* alps2 = alpd1 + N * 2;             // N
    float* alpd2 = alps2 + N;                 // N
    int* cnt     = (int*)(alpd2 + N);         // N
    int* rowptr  = cnt + N;                   // N+1
    int* bsum    = rowptr + N + 1;            // NB_SCAN
    int* boff    = bsum + NB_SCAN;            // NB_SCAN
    int* erank   = boff + NB_SCAN;            // EP
    int* csr_src = erank + EP;                // EP

    // ---- CSR build (shared by both layers) ----
    hipMemsetAsync(cnt, 0, N * sizeof(int), stream);
    hist_kernel<<<(EP + 255) / 256, 256, 0, stream>>>(ei, cnt, erank);
    partial_kernel<<<NB_SCAN, 256, 0, stream>>>(cnt, bsum);
    scanb_kernel<<<1, 256, 0, stream>>>(bsum, boff, rowptr);
    scanc_kernel<<<NB_SCAN, 256, 0, stream>>>(cnt, boff, rowptr);
    scatter_kernel<<<(EP + 255) / 256, 256, 0, stream>>>(ei, rowptr, erank, csr_src);

    // ---- layer 1 (H=2) ----
    gemm_alphas1<<<(N + 7) / 8, 64, 0, stream>>>(
        x, W1, h1b, as1w, ad1w, alps1, alpd1, (int)N);
    node_agg1_kernel<<<(N + 3) / 4, 256, 0, stream>>>(
        rowptr, csr_src, (const uint*)h1b, alps1, alpd1, b1, act1);

    // ---- layer 2 (H=1) ----
    gemm_alphas2<<<(N + 7) / 8, 64, 0, stream>>>(
        act1, W2, h2b, as2w, ad2w, alps2, alpd2, (int)N);
    node_agg2_kernel<<<(N + 3) / 4, 256, 0, stream>>>(
        rowptr, csr_src, h2b, alps2, alpd2, b2, out2);

    // ---- pool + fc + log_softmax ----
    pool_fc_kernel<<<N_GRAPHS, 256, 0, stream>>>(out2, batch, fcW, fcb, (float*)d_out);
}

// Round 11
// 291.330 us; speedup vs baseline: 8.9642x; 1.0658x over previous
//
#include <hip/hip_runtime.h>
#include <math.h>

#define N_NODES 50000
#define N_EDGES 800000
#define EP (N_EDGES + N_NODES)   // edges + self loops
#define IN_DIM 128
#define HID 64
#define HEADS 2
#define OUT_DIM 2
#define N_GRAPHS 512
#define NEG_SLOPE 0.2f
#define NB_SCAN 196              // ceil(50000/256)
#define G_GEMM1 1563             // ceil(50000/32) blocks of 4 waves x 8 nodes
#define G_HIST 3321              // ceil(850000/256)

typedef unsigned int uint;
typedef unsigned short ushort;

// round-to-nearest-even f32 -> bf16
__device__ __forceinline__ ushort f2bf(float f) {
    uint u = __float_as_uint(f);
    u += 0x7fffu + ((u >> 16) & 1u);
    return (ushort)(u >> 16);
}
__device__ __forceinline__ float bf_lo(uint u) { return __uint_as_float(u << 16); }
__device__ __forceinline__ float bf_hi(uint u) { return __uint_as_float(u & 0xffff0000u); }

// ---------- fused: layer-1 GEMM+alphas (blocks [0,G_GEMM1)) + histogram ----------
__global__ void fused_gemm1_hist(const float* __restrict__ X, const float* __restrict__ W,
                                 ushort* __restrict__ Y,
                                 const float* __restrict__ a_src, const float* __restrict__ a_dst,
                                 float* __restrict__ as, float* __restrict__ ad,
                                 const int* __restrict__ ei, int* __restrict__ cnt,
                                 int* __restrict__ erank) {
    if (blockIdx.x >= G_GEMM1) {
        // ---- histogram part: atomicAdd rank per edge ----
        int i = (blockIdx.x - G_GEMM1) * 256 + threadIdx.x;
        if (i < EP) {
            int d = (i < N_EDGES) ? ei[N_EDGES + i] : (i - N_EDGES);
            erank[i] = atomicAdd(&cnt[d], 1);
        }
        return;
    }
    // ---- gemm part: 4 waves, each 8 nodes; lane owns cols (lane, 64+lane) ----
    __shared__ float xs[32][128];
    const int wave = threadIdx.x >> 6;
    const int lane = threadIdx.x & 63;
    const int base = blockIdx.x * 32 + wave * 8;
    const float4* X4 = (const float4*)X;
    for (int idx = lane; idx < 8 * 32; idx += 64) {
        int r = idx >> 5, c = idx & 31;
        int n = base + r;
        float4 v = (n < N_NODES) ? X4[(size_t)n * 32 + c] : make_float4(0.f, 0.f, 0.f, 0.f);
        ((float4*)xs[wave * 8 + r])[c] = v;
    }
    __syncthreads();

    float acc0[8], acc1[8];
#pragma unroll
    for (int i = 0; i < 8; i++) { acc0[i] = 0.f; acc1[i] = 0.f; }
    for (int k = 0; k < 128; k += 4) {
        float wA[4], wB[4];
#pragma unroll
        for (int kk = 0; kk < 4; kk++) {
            wA[kk] = W[(size_t)(k + kk) * 128 + lane];
            wB[kk] = W[(size_t)(k + kk) * 128 + 64 + lane];
        }
#pragma unroll
        for (int i = 0; i < 8; i++) {
            float4 xv = *(const float4*)&xs[wave * 8 + i][k];
            acc0[i] = fmaf(xv.x, wA[0], acc0[i]); acc1[i] = fmaf(xv.x, wB[0], acc1[i]);
            acc0[i] = fmaf(xv.y, wA[1], acc0[i]); acc1[i] = fmaf(xv.y, wB[1], acc1[i]);
            acc0[i] = fmaf(xv.z, wA[2], acc0[i]); acc1[i] = fmaf(xv.z, wB[2], acc1[i]);
            acc0[i] = fmaf(xv.w, wA[3], acc0[i]); acc1[i] = fmaf(xv.w, wB[3], acc1[i]);
        }
    }

    const float asv0 = a_src[lane],      adv0 = a_dst[lane];
    const float asv1 = a_src[64 + lane], adv1 = a_dst[64 + lane];
#pragma unroll
    for (int i = 0; i < 8; i++) {
        int n = base + i;
        if (n >= N_NODES) continue;
        Y[(size_t)n * 128 + lane]      = f2bf(acc0[i]);
        Y[(size_t)n * 128 + 64 + lane] = f2bf(acc1[i]);
        float s0 = acc0[i] * asv0, d0 = acc0[i] * adv0;
        float s1 = acc1[i] * asv1, d1 = acc1[i] * adv1;
#pragma unroll
        for (int off = 32; off; off >>= 1) {
            s0 += __shfl_xor(s0, off);
            d0 += __shfl_xor(d0, off);
            s1 += __shfl_xor(s1, off);
            d1 += __shfl_xor(d1, off);
        }
        if (lane == 0) {
            as[(size_t)n * 2 + 0] = s0; as[(size_t)n * 2 + 1] = s1;
            ad[(size_t)n * 2 + 0] = d0; ad[(size_t)n * 2 + 1] = d1;
        }
    }
}

__global__ void partial_kernel(const int* __restrict__ cnt, int* __restrict__ bsum) {
    int tid = threadIdx.x;
    int i = blockIdx.x * 256 + tid;
    int lane = tid & 63, wid = tid >> 6;
    int v = (i < N_NODES) ? cnt[i] : 0;
#pragma unroll
    for (int off = 32; off; off >>= 1) v += __shfl_xor(v, off);
    __shared__ int wsum[4];
    if (lane == 0) wsum[wid] = v;
    __syncthreads();
    if (tid == 0) bsum[blockIdx.x] = wsum[0] + wsum[1] + wsum[2] + wsum[3];
}

__global__ void scanb_kernel(const int* __restrict__ bsum, int* __restrict__ boff,
                             int* __restrict__ rowptr) {
    int tid = threadIdx.x;          // 256
    int lane = tid & 63, wid = tid >> 6;
    int v = (tid < NB_SCAN) ? bsum[tid] : 0;
    int incl = v;
#pragma unroll
    for (int off = 1; off < 64; off <<= 1) {
        int t = __shfl_up(incl, off);
        if (lane >= off) incl += t;
    }
    __shared__ int wt[4];
    if (lane == 63) wt[wid] = incl;
    __syncthreads();
    int add = 0;
    for (int w = 0; w < wid; w++) add += wt[w];
    incl += add;
    if (tid < NB_SCAN) boff[tid] = incl - v;
    if (tid == NB_SCAN - 1) rowptr[N_NODES] = incl;
}

__global__ void scanc_kernel(const int* __restrict__ cnt, const int* __restrict__ boff,
                             int* __restrict__ rowptr) {
    int tid = threadIdx.x;
    int i = blockIdx.x * 256 + tid;
    int lane = tid & 63, wid = tid >> 6;
    int v = (i < N_NODES) ? cnt[i] : 0;
    int incl = v;
#pragma unroll
    for (int off = 1; off < 64; off <<= 1) {
        int t = __shfl_up(incl, off);
        if (lane >= off) incl += t;
    }
    __shared__ int wt[4];
    if (lane == 63) wt[wid] = incl;
    __syncthreads();
    int add = boff[blockIdx.x];
    for (int w = 0; w < wid; w++) add += wt[w];
    int excl = add + incl - v;
    if (i < N_NODES) rowptr[i] = excl;
}

// scatter with NO atomics: pos = rowptr[d] + erank[i]
__global__ void scatter_kernel(const int* __restrict__ ei, const int* __restrict__ rowptr,
                               const int* __restrict__ erank, int* __restrict__ csr_src) {
    int i = blockIdx.x * blockDim.x + threadIdx.x;
    if (i >= EP) return;
    int s, d;
    if (i < N_EDGES) { s = ei[i]; d = ei[N_EDGES + i]; }
    else             { s = d = i - N_EDGES; }
    csr_src[rowptr[d] + erank[i]] = s;
}

// ---------- layer-2 GEMM + fused alphas ----------
__global__ void gemm_alphas2(const float* __restrict__ X, const float* __restrict__ W,
                             ushort* __restrict__ Y,
                             const float* __restrict__ a_src, const float* __restrict__ a_dst,
                             float* __restrict__ as, float* __restrict__ ad, int n_nodes) {
    __shared__ float xs[8][128];
    const int base = blockIdx.x * 8;
    const int t = threadIdx.x;                 // 0..63
    const int g = t >> 5, c = t & 31;
    const float4* X4 = (const float4*)X;
    for (int idx = t; idx < 8 * 32; idx += 64) {
        int r = idx >> 5, cc = idx & 31;
        int n = base + r;
        float4 v = (n < n_nodes) ? X4[(size_t)n * 32 + cc] : make_float4(0.f, 0.f, 0.f, 0.f);
        ((float4*)xs[r])[cc] = v;
    }
    __syncthreads();

    float acc0[4], acc1[4];
#pragma unroll
    for (int i = 0; i < 4; i++) { acc0[i] = 0.f; acc1[i] = 0.f; }
    for (int k = 0; k < 128; k += 4) {
        float wA[4], wB[4];
#pragma unroll
        for (int kk = 0; kk < 4; kk++) {
            wA[kk] = W[(size_t)(k + kk) * 64 + c];
            wB[kk] = W[(size_t)(k + kk) * 64 + 32 + c];
        }
#pragma unroll
        for (int i = 0; i < 4; i++) {
            float4 xv = *(const float4*)&xs[g * 4 + i][k];
            acc0[i] = fmaf(xv.x, wA[0], acc0[i]); acc1[i] = fmaf(xv.x, wB[0], acc1[i]);
            acc0[i] = fmaf(xv.y, wA[1], acc0[i]); acc1[i] = fmaf(xv.y, wB[1], acc1[i]);
            acc0[i] = fmaf(xv.z, wA[2], acc0[i]); acc1[i] = fmaf(xv.z, wB[2], acc1[i]);
            acc0[i] = fmaf(xv.w, wA[3], acc0[i]); acc1[i] = fmaf(xv.w, wB[3], acc1[i]);
        }
    }

    const float asvA = a_src[c], asvB = a_src[32 + c];
    const float advA = a_dst[c], advB = a_dst[32 + c];
#pragma unroll
    for (int i = 0; i < 4; i++) {
        int n = base + g * 4 + i;
        if (n >= n_nodes) continue;
        Y[(size_t)n * 64 + c]      = f2bf(acc0[i]);
        Y[(size_t)n * 64 + 32 + c] = f2bf(acc1[i]);
        float s = acc0[i] * asvA + acc1[i] * asvB;
        float d = acc0[i] * advA + acc1[i] * advB;
#pragma unroll
        for (int off = 16; off; off >>= 1) {
            s += __shfl_xor(s, off);
            d += __shfl_xor(d, off);
        }
        if (c == 0) { as[n] = s; ad[n] = d; }
    }
}

__device__ __forceinline__ float lrelu(float e) { return e > 0.f ? e : NEG_SLOPE * e; }

// ---------- fused per-node softmax + aggregate + bias + relu ----------
__global__ void node_agg1_kernel(const int* __restrict__ rowptr, const int* __restrict__ csr_src,
                                 const uint* __restrict__ Hb,
                                 const float* __restrict__ as, const float* __restrict__ ad,
                                 const float* __restrict__ b, float* __restrict__ outp) {
    int wave = threadIdx.x >> 6;
    int lane = threadIdx.x & 63;
    int node = blockIdx.x * 4 + wave;
    if (node >= N_NODES) return;
    const int lo = rowptr[node], hi = rowptr[node + 1];
    const float ad0 = ad[(size_t)node * 2 + 0], ad1 = ad[(size_t)node * 2 + 1];

    float exa0 = 0.f, exa1 = 0.f, exb0 = 0.f, exb1 = 0.f;
    int j1 = lo + lane;
    if (j1 < hi) {
        int s = csr_src[j1];
        float2 a = *(const float2*)&as[(size_t)s * 2];
        exa0 = __expf(lrelu(a.x + ad0));
        exa1 = __expf(lrelu(a.y + ad1));
    }
    int j2 = lo + 64 + lane;
    if (j2 < hi) {
        int s = csr_src[j2];
        float2 a = *(const float2*)&as[(size_t)s * 2];
        exb0 = __expf(lrelu(a.x + ad0));
        exb1 = __expf(lrelu(a.y + ad1));
    }
    float d0 = exa0 + exb0, d1 = exa1 + exb1;
    for (int j = lo + 128 + lane; j < hi; j += 64) {   // degree > 128 (rare)
        int s = csr_src[j];
        float2 a = *(const float2*)&as[(size_t)s * 2];
        d0 += __expf(lrelu(a.x + ad0));
        d1 += __expf(lrelu(a.y + ad1));
    }
#pragma unroll
    for (int off = 32; off; off >>= 1) {
        d0 += __shfl_xor(d0, off);
        d1 += __shfl_xor(d1, off);
    }
    const float inv = (lane < 32) ? (1.f / d0) : (1.f / d1);
    const bool h0side = (lane < 32);

    float acc0 = 0.f, acc1 = 0.f;
    const int deg = hi - lo;
    const int n1 = deg < 64 ? deg : 64;
    int j = 0;
    for (; j + 8 <= n1; j += 8) {
        int s0 = csr_src[lo + j + 0], s1 = csr_src[lo + j + 1];
        int s2 = csr_src[lo + j + 2], s3 = csr_src[lo + j + 3];
        int s4 = csr_src[lo + j + 4], s5 = csr_src[lo + j + 5];
        int s6 = csr_src[lo + j + 6], s7 = csr_src[lo + j + 7];
        uint u0 = Hb[(size_t)s0 * 64 + lane];
        uint u1 = Hb[(size_t)s1 * 64 + lane];
        uint u2 = Hb[(size_t)s2 * 64 + lane];
        uint u3 = Hb[(size_t)s3 * 64 + lane];
        uint u4 = Hb[(size_t)s4 * 64 + lane];
        uint u5 = Hb[(size_t)s5 * 64 + lane];
        uint u6 = Hb[(size_t)s6 * 64 + lane];
        uint u7 = Hb[(size_t)s7 * 64 + lane];
        float ca0 = __shfl(exa0, j + 0), cb0 = __shfl(exa1, j + 0);
        float ca1 = __shfl(exa0, j + 1), cb1 = __shfl(exa1, j + 1);
        float ca2 = __shfl(exa0, j + 2), cb2 = __shfl(exa1, j + 2);
        float ca3 = __shfl(exa0, j + 3), cb3 = __shfl(exa1, j + 3);
        float ca4 = __shfl(exa0, j + 4), cb4 = __shfl(exa1, j + 4);
        float ca5 = __shfl(exa0, j + 5), cb5 = __shfl(exa1, j + 5);
        float ca6 = __shfl(exa0, j + 6), cb6 = __shfl(exa1, j + 6);
        float ca7 = __shfl(exa0, j + 7), cb7 = __shfl(exa1, j + 7);
        float c0 = h0side ? ca0 : cb0;
        float c1 = h0side ? ca1 : cb1;
        float c2 = h0side ? ca2 : cb2;
        float c3 = h0side ? ca3 : cb3;
        float c4 = h0side ? ca4 : cb4;
        float c5 = h0side ? ca5 : cb5;
        float c6 = h0side ? ca6 : cb6;
        float c7 = h0side ? ca7 : cb7;
        acc0 = fmaf(bf_lo(u0), c0, acc0); acc1 = fmaf(bf_hi(u0), c0, acc1);
        acc0 = fmaf(bf_lo(u1), c1, acc0); acc1 = fmaf(bf_hi(u1), c1, acc1);
        acc0 = fmaf(bf_lo(u2), c2, acc0); acc1 = fmaf(bf_hi(u2), c2, acc1);
        acc0 = fmaf(bf_lo(u3), c3, acc0); acc1 = fmaf(bf_hi(u3), c3, acc1);
        acc0 = fmaf(bf_lo(u4), c4, acc0); acc1 = fmaf(bf_hi(u4), c4, acc1);
        acc0 = fmaf(bf_lo(u5), c5, acc0); acc1 = fmaf(bf_hi(u5), c5, acc1);
        acc0 = fmaf(bf_lo(u6), c6, acc0); acc1 = fmaf(bf_hi(u6), c6, acc1);
        acc0 = fmaf(bf_lo(u7), c7, acc0); acc1 = fmaf(bf_hi(u7), c7, acc1);
    }
    for (; j < n1; j++) {
        int s = csr_src[lo + j];
        float ca = __shfl(exa0, j), cb = __shfl(exa1, j);
        float c = h0side ? ca : cb;
        uint u = Hb[(size_t)s * 64 + lane];
        acc0 = fmaf(bf_lo(u), c, acc0);
        acc1 = fmaf(bf_hi(u), c, acc1);
    }
    if (deg > 64) {
        const int n2 = deg < 128 ? deg : 128;
        for (j = 64; j < n2; j++) {
            int s = csr_src[lo + j];
            float ca = __shfl(exb0, j - 64), cb = __shfl(exb1, j - 64);
            float c = h0side ? ca : cb;
            uint u = Hb[(size_t)s * 64 + lane];
            acc0 = fmaf(bf_lo(u), c, acc0);
            acc1 = fmaf(bf_hi(u), c, acc1);
        }
        for (int jj = lo + 128; jj < hi; jj++) {       // rare; lane-local, no shfl
            int s = csr_src[jj];
            float2 a = *(const float2*)&as[(size_t)s * 2];
            float e0 = __expf(lrelu(a.x + ad0));
            float e1 = __expf(lrelu(a.y + ad1));
            float c = h0side ? e0 : e1;
            uint u = Hb[(size_t)s * 64 + lane];
            acc0 = fmaf(bf_lo(u), c, acc0);
            acc1 = fmaf(bf_hi(u), c, acc1);
        }
    }
    float v0 = acc0 * inv + b[2 * lane];
    float v1 = acc1 * inv + b[2 * lane + 1];
    v0 = v0 > 0.f ? v0 : 0.f;
    v1 = v1 > 0.f ? v1 : 0.f;
    *(float2*)&outp[(size_t)node * 128 + 2 * lane] = make_float2(v0, v1);
}

__global__ void node_agg2_kernel(const int* __restrict__ rowptr, const int* __restrict__ csr_src,
                                 const ushort* __restrict__ Hb,
                                 const float* __restrict__ as, const float* __restrict__ ad,
                                 const float* __restrict__ b, float* __restrict__ outp) {
    int wave = threadIdx.x >> 6;
    int lane = threadIdx.x & 63;
    int node = blockIdx.x * 4 + wave;
    if (node >= N_NODES) return;
    const int lo = rowptr[node], hi = rowptr[node + 1];
    const float adN = ad[node];

    float exa = 0.f, exb = 0.f;
    int j1 = lo + lane;
    if (j1 < hi) exa = __expf(lrelu(as[csr_src[j1]] + adN));
    int j2 = lo + 64 + lane;
    if (j2 < hi) exb = __expf(lrelu(as[csr_src[j2]] + adN));
    float d = exa + exb;
    for (int j = lo + 128 + lane; j < hi; j += 64)
        d += __expf(lrelu(as[csr_src[j]] + adN));
#pragma unroll
    for (int off = 32; off; off >>= 1) d += __shfl_xor(d, off);
    const float inv = 1.f / d;

    float acc = 0.f;
    const int deg = hi - lo;
    const int n1 = deg < 64 ? deg : 64;
    int j = 0;
    for (; j + 8 <= n1; j += 8) {
        int s0 = csr_src[lo + j + 0], s1 = csr_src[lo + j + 1];
        int s2 = csr_src[lo + j + 2], s3 = csr_src[lo + j + 3];
        int s4 = csr_src[lo + j + 4], s5 = csr_src[lo + j + 5];
        int s6 = csr_src[lo + j + 6], s7 = csr_src[lo + j + 7];
        float h0 = __uint_as_float(((uint)Hb[(size_t)s0 * 64 + lane]) << 16);
        float h1 = __uint_as_float(((uint)Hb[(size_t)s1 * 64 + lane]) << 16);
        float h2 = __uint_as_float(((uint)Hb[(size_t)s2 * 64 + lane]) << 16);
        float h3 = __uint_as_float(((uint)Hb[(size_t)s3 * 64 + lane]) << 16);
        float h4 = __uint_as_float(((uint)Hb[(size_t)s4 * 64 + lane]) << 16);
        float h5 = __uint_as_float(((uint)Hb[(size_t)s5 * 64 + lane]) << 16);
        float h6 = __uint_as_float(((uint)Hb[(size_t)s6 * 64 + lane]) << 16);
        float h7 = __uint_as_float(((uint)Hb[(size_t)s7 * 64 + lane]) << 16);
        float c0 = __shfl(exa, j + 0), c1 = __shfl(exa, j + 1);
        float c2 = __shfl(exa, j + 2), c3 = __shfl(exa, j + 3);
        float c4 = __shfl(exa, j + 4), c5 = __shfl(exa, j + 5);
        float c6 = __shfl(exa, j + 6), c7 = __shfl(exa, j + 7);
        acc = fmaf(h0, c0, acc);
        acc = fmaf(h1, c1, acc);
        acc = fmaf(h2, c2, acc);
        acc = fmaf(h3, c3, acc);
        acc = fmaf(h4, c4, acc);
        acc = fmaf(h5, c5, acc);
        acc = fmaf(h6, c6, acc);
        acc = fmaf(h7, c7, acc);
    }
    for (; j < n1; j++) {
        float c = __shfl(exa, j);
        acc = fmaf(__uint_as_float(((uint)Hb[(size_t)csr_src[lo + j] * 64 + lane]) << 16), c, acc);
    }
    if (deg > 64) {
        const int n2 = deg < 128 ? deg : 128;
        for (j = 64; j < n2; j++) {
            float c = __shfl(exb, j - 64);
            acc = fmaf(__uint_as_float(((uint)Hb[(size_t)csr_src[lo + j] * 64 + lane]) << 16), c, acc);
        }
        for (int jj = lo + 128; jj < hi; jj++) {       // rare
            int s = csr_src[jj];
            float c = __expf(lrelu(as[s] + adN));
            acc = fmaf(__uint_as_float(((uint)Hb[(size_t)s * 64 + lane]) << 16), c, acc);
        }
    }
    float v = acc * inv + b[lane];
    outp[(size_t)node * 64 + lane] = v > 0.f ? v : 0.f;
}

// ---------- pool + fc + log_softmax: 4 waves per graph ----------
__global__ void pool_fc_kernel(const float* __restrict__ act2,
                               const int* __restrict__ batch,
                               const float* __restrict__ fcW,
                               const float* __restrict__ fcb,
                               float* __restrict__ out) {
    int g = blockIdx.x;
    int tid = threadIdx.x;            // 256
    int wid = tid >> 6, c = tid & 63;
    __shared__ int slo, shi;
    if (tid == 0) {
        int lo = 0, hi = N_NODES;
        while (lo < hi) { int m = (lo + hi) >> 1; if (batch[m] < g) lo = m + 1; else hi = m; }
        slo = lo;
        lo = 0; hi = N_NODES;
        while (lo < hi) { int m = (lo + hi) >> 1; if (batch[m] < g + 1) lo = m + 1; else hi = m; }
        shi = lo;
    }
    __syncthreads();
    const int lo = slo, hi = shi;
    float sum = 0.f;
    for (int n = lo + wid; n < hi; n += 4) sum += act2[(size_t)n * HID + c];
    __shared__ float ps[4][HID];
    ps[wid][c] = sum;
    __syncthreads();
    if (wid == 0) {
        float t = ps[0][c] + ps[1][c] + ps[2][c] + ps[3][c];
        float cnt = (float)(hi - lo);
        __shared__ float pooled[HID];
        pooled[c] = t / fmaxf(cnt, 1.f);
        __syncthreads();
        __shared__ float ls[OUT_DIM];
        if (c < OUT_DIM) {
            float l = fcb[c];
#pragma unroll 8
            for (int k = 0; k < HID; k++) l = fmaf(pooled[k], fcW[k * OUT_DIM + c], l);
            ls[c] = l;
        }
        __syncthreads();
        if (c < OUT_DIM) {
            float m = fmaxf(ls[0], ls[1]);
            float lse = m + logf(expf(ls[0] - m) + expf(ls[1] - m));
            out[(size_t)g * OUT_DIM + c] = ls[c] - lse;
        }
    }
}

extern "C" void kernel_launch(void* const* d_in, const int* in_sizes, int n_in,
                              void* d_out, int out_size, void* d_ws, size_t ws_size,
                              hipStream_t stream) {
    const float* x    = (const float*)d_in[0];
    const int*   ei   = (const int*)d_in[1];
    const int*   batch= (const int*)d_in[2];
    const float* W1   = (const float*)d_in[3];
    const float* as1w = (const float*)d_in[4];
    const float* ad1w = (const float*)d_in[5];
    const float* b1   = (const float*)d_in[6];
    const float* W2   = (const float*)d_in[7];
    const float* as2w = (const float*)d_in[8];
    const float* ad2w = (const float*)d_in[9];
    const float* b2   = (const float*)d_in[10];
    const float* fcW  = (const float*)d_in[11];
    const float* fcb  = (const float*)d_in[12];

    const size_t N = N_NODES;
    float* ws = (float*)d_ws;
    ushort* h1b  = (ushort*)ws;               // N*128 bf16 = N*64 floats
    float* act1  = ws + N * 64;               // N*128 fp32
    ushort* h2b  = (ushort*)(act1 + N * 128); // N*64 bf16 = N*32 floats
    float* out2  = act1 + N * 128 + N * 32;   // N*64 fp32
    float* alps1 = out2 + N * 64;             // N*2
    float* alpd1 = alps1 + N * 2;             // N*2
    float* alps2 = alpd1 + N * 2;             // N
    float* alpd2 = alps2 + N;                 // N
    int* cnt     = (int*)(alpd2 + N);         // N
    int* rowptr  = cnt + N;                   // N+1
    int* bsum    = rowptr + N + 1;            // NB_SCAN
    int* boff    = bsum + NB_SCAN;            // NB_SCAN
    int* erank   = boff + NB_SCAN;            // EP
    int* csr_src = erank + EP;                // EP

    // ---- fused: layer-1 GEMM+alphas || edge histogram ----
    hipMemsetAsync(cnt, 0, N * sizeof(int), stream);
    fused_gemm1_hist<<<G_GEMM1 + G_HIST, 256, 0, stream>>>(
        x, W1, h1b, as1w, ad1w, alps1, alpd1, ei, cnt, erank);

    // ---- CSR finish ----
    partial_kernel<<<NB_SCAN, 256, 0, stream>>>(cnt, bsum);
    scanb_kernel<<<1, 256, 0, stream>>>(bsum, boff, rowptr);
    scanc_kernel<<<NB_SCAN, 256, 0, stream>>>(cnt, boff, rowptr);
    scatter_kernel<<<(EP + 255) / 256, 256, 0, stream>>>(ei, rowptr, erank, csr_src);

    // ---- layer 1 aggregate ----
    node_agg1_kernel<<<(N + 3) / 4, 256, 0, stream>>>(
        rowptr, csr_src, (const uint*)h1b, alps1, alpd1, b1, act1);

    // ---- layer 2 ----
    gemm_alphas2<<<(N + 7) / 8, 64, 0, stream>>>(
        act1, W2, h2b, as2w, ad2w, alps2, alpd2, (int)N);
    node_agg2_kernel<<<(N + 3) / 4, 256, 0, stream>>>(
        rowptr, csr_src, h2b, alps2, alpd2, b2, out2);

    // ---- pool + fc + log_softmax ----
    pool_fc_kernel<<<N_GRAPHS, 256, 0, stream>>>(out2, batch, fcW, fcb, (float*)d_out);
}